// Round 1
// baseline (1157.904 us; speedup 1.0000x reference)
//
#include <hip/hip_runtime.h>
#include <math.h>

#define N_NODES 100000
#define N_EDGES 1600000
#define SLOPE 0.2f
#define SCAN_BLK 1024  // elements per scan block (256 threads * 4)

// ----------------- CSR build -----------------
__global__ void hist_kernel(const int* __restrict__ ei, int* __restrict__ hist,
                            int E, int n) {
  int e = blockIdx.x * blockDim.x + threadIdx.x;
  int total = E + n;
  if (e >= total) return;
  int d = (e < E) ? ei[E + e] : (e - E);
  atomicAdd(&hist[d], 1);
}

__global__ void scan_blocks(const int* __restrict__ in, int* __restrict__ incl,
                            int* __restrict__ bsum, int n) {
  __shared__ int lds[256];
  int t = threadIdx.x;
  int base = blockIdx.x * SCAN_BLK + t * 4;
  int v[4];
#pragma unroll
  for (int i = 0; i < 4; i++) v[i] = (base + i < n) ? in[base + i] : 0;
  v[1] += v[0]; v[2] += v[1]; v[3] += v[2];
  int x = v[3];
  lds[t] = x;
  __syncthreads();
  for (int off = 1; off < 256; off <<= 1) {
    int y = (t >= off) ? lds[t - off] : 0;
    __syncthreads();
    x += y;
    lds[t] = x;
    __syncthreads();
  }
  int excl = x - v[3];
#pragma unroll
  for (int i = 0; i < 4; i++)
    if (base + i < n) incl[base + i] = v[i] + excl;
  if (t == 255) bsum[blockIdx.x] = x;
}

__global__ void scan_bsum(int* bsum, int nb) {
  __shared__ int lds[128];
  int t = threadIdx.x;
  int orig = (t < nb) ? bsum[t] : 0;
  int x = orig;
  lds[t] = x;
  __syncthreads();
  for (int off = 1; off < 128; off <<= 1) {
    int y = (t >= off) ? lds[t - off] : 0;
    __syncthreads();
    x += y;
    lds[t] = x;
    __syncthreads();
  }
  if (t < nb) bsum[t] = x - orig;  // exclusive block offsets
}

__global__ void finalize_rows(const int* __restrict__ incl,
                              const int* __restrict__ bsum,
                              int* __restrict__ row_start, int n) {
  int i = blockIdx.x * blockDim.x + threadIdx.x;
  if (i < n) row_start[i + 1] = incl[i] + bsum[i / SCAN_BLK];
  if (i == 0) row_start[0] = 0;
}

__global__ void scatter_kernel(const int* __restrict__ ei,
                               const int* __restrict__ row_start,
                               int* __restrict__ cursor,
                               int* __restrict__ edge_src, int E, int n) {
  int e = blockIdx.x * blockDim.x + threadIdx.x;
  int total = E + n;
  if (e >= total) return;
  int s, d;
  if (e < E) { s = ei[e]; d = ei[E + e]; } else { s = e - E; d = e - E; }
  int pos = row_start[d] + atomicAdd(&cursor[d], 1);
  edge_src[pos] = s;
}

// ----------------- GEMM [n,128] x [128,128] fp32 -----------------
__global__ __launch_bounds__(256) void gemm128(const float* __restrict__ X,
                                               const float* __restrict__ W,
                                               float* __restrict__ Y, int n) {
  __shared__ float xs[32 * 128];
  int t = threadIdx.x;
  int rowBase = blockIdx.x * 32;
  const float4* Xv = (const float4*)(X + (size_t)rowBase * 128);
  float4* xsv = (float4*)xs;
#pragma unroll
  for (int i = 0; i < 4; i++) xsv[t + i * 256] = Xv[t + i * 256];
  __syncthreads();
  int tx = t & 31, ty = t >> 5;
  float acc[4][4] = {};
  const float* Wc = W + tx * 4;
  for (int k = 0; k < 128; k += 4) {
    float4 w0 = *(const float4*)(Wc + (k + 0) * 128);
    float4 w1 = *(const float4*)(Wc + (k + 1) * 128);
    float4 w2 = *(const float4*)(Wc + (k + 2) * 128);
    float4 w3 = *(const float4*)(Wc + (k + 3) * 128);
#pragma unroll
    for (int r = 0; r < 4; r++) {
      int row = ty + r * 8;
      float4 xv = *(const float4*)(xs + row * 128 + k);
      acc[r][0] += xv.x * w0.x + xv.y * w1.x + xv.z * w2.x + xv.w * w3.x;
      acc[r][1] += xv.x * w0.y + xv.y * w1.y + xv.z * w2.y + xv.w * w3.y;
      acc[r][2] += xv.x * w0.z + xv.y * w1.z + xv.z * w2.z + xv.w * w3.z;
      acc[r][3] += xv.x * w0.w + xv.y * w1.w + xv.z * w2.w + xv.w * w3.w;
    }
  }
#pragma unroll
  for (int r = 0; r < 4; r++) {
    int row = rowBase + ty + r * 8;
    float4 o;
    o.x = acc[r][0]; o.y = acc[r][1]; o.z = acc[r][2]; o.w = acc[r][3];
    *(float4*)(Y + (size_t)row * 128 + tx * 4) = o;
  }
}

// ----------------- per-node attention dots -----------------
template <int H>
__global__ __launch_bounds__(256) void att_kernel(
    const float* __restrict__ h, const float* __restrict__ att_src,
    const float* __restrict__ att_dst, float* __restrict__ a_s,
    float* __restrict__ a_d, int n) {
  const int C = 128 / H;
  int wid = (blockIdx.x * blockDim.x + threadIdx.x) >> 6;
  int lane = threadIdx.x & 63;
  if (wid >= n) return;
  int d0 = lane * 2;
  int head = d0 / C;
  int c0 = d0 % C;
  float2 hv = *(const float2*)(h + (size_t)wid * 128 + d0);
  float2 asv = *(const float2*)(att_src + head * C + c0);
  float2 adv = *(const float2*)(att_dst + head * C + c0);
  float ps = hv.x * asv.x + hv.y * asv.y;
  float pd = hv.x * adv.x + hv.y * adv.y;
  for (int off = 1; off < C / 2; off <<= 1) {
    ps += __shfl_xor(ps, off, 64);
    pd += __shfl_xor(pd, off, 64);
  }
  if (c0 == 0) {
    a_s[wid * H + head] = ps;
    a_d[wid * H + head] = pd;
  }
}

// ----------------- softmax + aggregation, one wave per dst node ----------
template <int H, bool DO_ELU>
__global__ __launch_bounds__(256) void agg_kernel(
    const float* __restrict__ h, const float* __restrict__ a_s,
    const float* __restrict__ a_d, const int* __restrict__ row_start,
    const int* __restrict__ edge_src, const float* __restrict__ bias,
    float* __restrict__ out, int n) {
  const int C = 128 / H;
  const int G = C / 2;  // lanes per head
  int wid = (blockIdx.x * blockDim.x + threadIdx.x) >> 6;
  int lane = threadIdx.x & 63;
  if (wid >= n) return;
  int head = lane / G;
  int start = row_start[wid], end = row_start[wid + 1];

  float adv[H];
#pragma unroll
  for (int hh = 0; hh < H; hh++) adv[hh] = a_d[wid * H + hh];

  // pass 1: online softmax stats per head, edges distributed across lanes
  float m[H], s[H];
#pragma unroll
  for (int hh = 0; hh < H; hh++) { m[hh] = -1e30f; s[hh] = 0.f; }
  for (int idx = start + lane; idx < end; idx += 64) {
    int sn = edge_src[idx];
#pragma unroll
    for (int hh = 0; hh < H; hh++) {
      float e = a_s[sn * H + hh] + adv[hh];
      e = (e >= 0.f) ? e : SLOPE * e;
      float mn = fmaxf(m[hh], e);
      s[hh] = s[hh] * __expf(m[hh] - mn) + __expf(e - mn);
      m[hh] = mn;
    }
  }
  // butterfly merge so every lane ends with the full (m,s)
  for (int off = 1; off < 64; off <<= 1) {
#pragma unroll
    for (int hh = 0; hh < H; hh++) {
      float mo = __shfl_xor(m[hh], off, 64);
      float so = __shfl_xor(s[hh], off, 64);
      float mn = fmaxf(m[hh], mo);
      s[hh] = s[hh] * __expf(m[hh] - mn) + so * __expf(mo - mn);
      m[hh] = mn;
    }
  }

  // pass 2: weighted aggregation; each lane owns dims (2*lane, 2*lane+1)
  int d0 = lane * 2;
  float mh = m[head];
  float rsh = 1.f / s[head];
  float adh = adv[head];
  float acc0 = 0.f, acc1 = 0.f;
  for (int idx = start; idx < end; idx++) {
    int sn = edge_src[idx];
    float e = a_s[sn * H + head] + adh;
    e = (e >= 0.f) ? e : SLOPE * e;
    float w = __expf(e - mh) * rsh;
    float2 hv = *(const float2*)(h + (size_t)sn * 128 + d0);
    acc0 += w * hv.x;
    acc1 += w * hv.y;
  }
  float o0 = acc0 + bias[d0];
  float o1 = acc1 + bias[d0 + 1];
  if (DO_ELU) {
    o0 = (o0 > 0.f) ? o0 : __expf(o0) - 1.f;
    o1 = (o1 > 0.f) ? o1 : __expf(o1) - 1.f;
  }
  out[(size_t)wid * 128 + d0] = o0;
  out[(size_t)wid * 128 + d0 + 1] = o1;
}

extern "C" void kernel_launch(void* const* d_in, const int* in_sizes, int n_in,
                              void* d_out, int out_size, void* d_ws,
                              size_t ws_size, hipStream_t stream) {
  const float* x = (const float*)d_in[0];
  const int* ei = (const int*)d_in[1];
  const float* W1 = (const float*)d_in[2];
  const float* as1 = (const float*)d_in[3];
  const float* ad1 = (const float*)d_in[4];
  const float* b1 = (const float*)d_in[5];
  const float* W2 = (const float*)d_in[6];
  const float* as2 = (const float*)d_in[7];
  const float* ad2 = (const float*)d_in[8];
  const float* b2 = (const float*)d_in[9];
  const float* W3 = (const float*)d_in[10];
  const float* as3 = (const float*)d_in[11];
  const float* ad3 = (const float*)d_in[12];
  const float* b3 = (const float*)d_in[13];
  float* out = (float*)d_out;

  const int n = N_NODES, E = N_EDGES, total = E + n;

  char* ws = (char*)d_ws;
  size_t off = 0;
  auto alloc = [&](size_t bytes) -> char* {
    char* p = ws + off;
    off = (off + bytes + 255) & ~(size_t)255;
    return p;
  };
  float* hbuf = (float*)alloc(sizeof(float) * (size_t)n * 128);  // 51.2 MB
  float* a_s = (float*)alloc(sizeof(float) * n * 4);
  float* a_d = (float*)alloc(sizeof(float) * n * 4);
  int* hist = (int*)alloc(sizeof(int) * n);
  int* incl = (int*)alloc(sizeof(int) * n);
  int* bsum = (int*)alloc(sizeof(int) * 256);
  int* row_start = (int*)alloc(sizeof(int) * (n + 1));
  int* cursor = (int*)alloc(sizeof(int) * n);
  int* edge_src = (int*)alloc(sizeof(int) * total);  // 6.8 MB

  hipMemsetAsync(hist, 0, sizeof(int) * n, stream);
  hipMemsetAsync(cursor, 0, sizeof(int) * n, stream);

  // CSR build (graph is shared by all 3 layers)
  hist_kernel<<<(total + 255) / 256, 256, 0, stream>>>(ei, hist, E, n);
  int nb = (n + SCAN_BLK - 1) / SCAN_BLK;  // 98
  scan_blocks<<<nb, 256, 0, stream>>>(hist, incl, bsum, n);
  scan_bsum<<<1, 128, 0, stream>>>(bsum, nb);
  finalize_rows<<<(n + 255) / 256, 256, 0, stream>>>(incl, bsum, row_start, n);
  scatter_kernel<<<(total + 255) / 256, 256, 0, stream>>>(ei, row_start, cursor,
                                                          edge_src, E, n);

  int agg_blocks = (n + 3) / 4;  // one wave per node, 4 waves/block

  // layer 1: x -> hbuf -> out (ELU)
  gemm128<<<n / 32, 256, 0, stream>>>(x, W1, hbuf, n);
  att_kernel<4><<<agg_blocks, 256, 0, stream>>>(hbuf, as1, ad1, a_s, a_d, n);
  agg_kernel<4, true><<<agg_blocks, 256, 0, stream>>>(
      hbuf, a_s, a_d, row_start, edge_src, b1, out, n);

  // layer 2: out -> hbuf -> out (ELU)
  gemm128<<<n / 32, 256, 0, stream>>>(out, W2, hbuf, n);
  att_kernel<4><<<agg_blocks, 256, 0, stream>>>(hbuf, as2, ad2, a_s, a_d, n);
  agg_kernel<4, true><<<agg_blocks, 256, 0, stream>>>(
      hbuf, a_s, a_d, row_start, edge_src, b2, out, n);

  // layer 3: out -> hbuf -> out (no ELU), heads=1
  gemm128<<<n / 32, 256, 0, stream>>>(out, W3, hbuf, n);
  att_kernel<1><<<agg_blocks, 256, 0, stream>>>(hbuf, as3, ad3, a_s, a_d, n);
  agg_kernel<1, false><<<agg_blocks, 256, 0, stream>>>(
      hbuf, a_s, a_d, row_start, edge_src, b3, out, n);
}

// Round 2
// 943.035 us; speedup vs baseline: 1.2278x; 1.2278x over previous
//
#include <hip/hip_runtime.h>
#include <math.h>

#define N_NODES 100000
#define N_EDGES 1600000
#define SLOPE 0.2f
#define SCAN_BLK 1024  // elements per scan block (256 threads * 4)

// ----------------- CSR build -----------------
__global__ void hist_kernel(const int* __restrict__ ei, int* __restrict__ hist,
                            int E, int n) {
  int e = blockIdx.x * blockDim.x + threadIdx.x;
  int total = E + n;
  if (e >= total) return;
  int d = (e < E) ? ei[E + e] : (e - E);
  atomicAdd(&hist[d], 1);
}

__global__ void scan_blocks(const int* __restrict__ in, int* __restrict__ incl,
                            int* __restrict__ bsum, int n) {
  __shared__ int lds[256];
  int t = threadIdx.x;
  int base = blockIdx.x * SCAN_BLK + t * 4;
  int v[4];
#pragma unroll
  for (int i = 0; i < 4; i++) v[i] = (base + i < n) ? in[base + i] : 0;
  v[1] += v[0]; v[2] += v[1]; v[3] += v[2];
  int x = v[3];
  lds[t] = x;
  __syncthreads();
  for (int off = 1; off < 256; off <<= 1) {
    int y = (t >= off) ? lds[t - off] : 0;
    __syncthreads();
    x += y;
    lds[t] = x;
    __syncthreads();
  }
  int excl = x - v[3];
#pragma unroll
  for (int i = 0; i < 4; i++)
    if (base + i < n) incl[base + i] = v[i] + excl;
  if (t == 255) bsum[blockIdx.x] = x;
}

__global__ void scan_bsum(int* bsum, int nb) {
  __shared__ int lds[128];
  int t = threadIdx.x;
  int orig = (t < nb) ? bsum[t] : 0;
  int x = orig;
  lds[t] = x;
  __syncthreads();
  for (int off = 1; off < 128; off <<= 1) {
    int y = (t >= off) ? lds[t - off] : 0;
    __syncthreads();
    x += y;
    lds[t] = x;
    __syncthreads();
  }
  if (t < nb) bsum[t] = x - orig;  // exclusive block offsets
}

__global__ void finalize_rows(const int* __restrict__ incl,
                              const int* __restrict__ bsum,
                              int* __restrict__ row_start, int n) {
  int i = blockIdx.x * blockDim.x + threadIdx.x;
  if (i < n) row_start[i + 1] = incl[i] + bsum[i / SCAN_BLK];
  if (i == 0) row_start[0] = 0;
}

__global__ void scatter_kernel(const int* __restrict__ ei,
                               const int* __restrict__ row_start,
                               int* __restrict__ cursor,
                               int* __restrict__ edge_src, int E, int n) {
  int e = blockIdx.x * blockDim.x + threadIdx.x;
  int total = E + n;
  if (e >= total) return;
  int s, d;
  if (e < E) { s = ei[e]; d = ei[E + e]; } else { s = e - E; d = e - E; }
  int pos = row_start[d] + atomicAdd(&cursor[d], 1);
  edge_src[pos] = s;
}

// ----------------- GEMM [n,128] x [128,128] fp32 -----------------
__global__ __launch_bounds__(256) void gemm128(const float* __restrict__ X,
                                               const float* __restrict__ W,
                                               float* __restrict__ Y, int n) {
  __shared__ float xs[32 * 128];
  int t = threadIdx.x;
  int rowBase = blockIdx.x * 32;
  const float4* Xv = (const float4*)(X + (size_t)rowBase * 128);
  float4* xsv = (float4*)xs;
#pragma unroll
  for (int i = 0; i < 4; i++) xsv[t + i * 256] = Xv[t + i * 256];
  __syncthreads();
  int tx = t & 31, ty = t >> 5;
  float acc[4][4] = {};
  const float* Wc = W + tx * 4;
  for (int k = 0; k < 128; k += 4) {
    float4 w0 = *(const float4*)(Wc + (k + 0) * 128);
    float4 w1 = *(const float4*)(Wc + (k + 1) * 128);
    float4 w2 = *(const float4*)(Wc + (k + 2) * 128);
    float4 w3 = *(const float4*)(Wc + (k + 3) * 128);
#pragma unroll
    for (int r = 0; r < 4; r++) {
      int row = ty + r * 8;
      float4 xv = *(const float4*)(xs + row * 128 + k);
      acc[r][0] += xv.x * w0.x + xv.y * w1.x + xv.z * w2.x + xv.w * w3.x;
      acc[r][1] += xv.x * w0.y + xv.y * w1.y + xv.z * w2.y + xv.w * w3.y;
      acc[r][2] += xv.x * w0.z + xv.y * w1.z + xv.z * w2.z + xv.w * w3.z;
      acc[r][3] += xv.x * w0.w + xv.y * w1.w + xv.z * w2.w + xv.w * w3.w;
    }
  }
#pragma unroll
  for (int r = 0; r < 4; r++) {
    int row = rowBase + ty + r * 8;
    float4 o;
    o.x = acc[r][0]; o.y = acc[r][1]; o.z = acc[r][2]; o.w = acc[r][3];
    *(float4*)(Y + (size_t)row * 128 + tx * 4) = o;
  }
}

// ----------------- per-node attention dots -----------------
template <int H>
__global__ __launch_bounds__(256) void att_kernel(
    const float* __restrict__ h, const float* __restrict__ att_src,
    const float* __restrict__ att_dst, float* __restrict__ a_s,
    float* __restrict__ a_d, int n) {
  const int C = 128 / H;
  int wid = (blockIdx.x * blockDim.x + threadIdx.x) >> 6;
  int lane = threadIdx.x & 63;
  if (wid >= n) return;
  int d0 = lane * 2;
  int head = d0 / C;
  int c0 = d0 % C;
  float2 hv = *(const float2*)(h + (size_t)wid * 128 + d0);
  float2 asv = *(const float2*)(att_src + head * C + c0);
  float2 adv = *(const float2*)(att_dst + head * C + c0);
  float ps = hv.x * asv.x + hv.y * asv.y;
  float pd = hv.x * adv.x + hv.y * adv.y;
  for (int off = 1; off < C / 2; off <<= 1) {
    ps += __shfl_xor(ps, off, 64);
    pd += __shfl_xor(pd, off, 64);
  }
  if (c0 == 0) {
    a_s[wid * H + head] = ps;
    a_d[wid * H + head] = pd;
  }
}

// ----------------- softmax + aggregation, one wave per dst node ----------
// Fast path (deg <= 64): one edge per lane; max-butterfly -> single exp ->
// sum-butterfly; normalized weights + src ids cached in LDS; then 4 edges
// in flight (16 lanes x 8 dims each) for the gather-accumulate.
template <int H, bool DO_ELU>
__global__ __launch_bounds__(256) void agg_kernel(
    const float* __restrict__ h, const float* __restrict__ a_s,
    const float* __restrict__ a_d, const int* __restrict__ row_start,
    const int* __restrict__ edge_src, const float* __restrict__ bias,
    float* __restrict__ out, int n) {
  const int C = 128 / H;
  __shared__ float w_lds[4][H * 66];
  __shared__ int sn_lds[4][64];
  int wslot = threadIdx.x >> 6;
  int wid = (blockIdx.x * blockDim.x + threadIdx.x) >> 6;
  int lane = threadIdx.x & 63;
  if (wid >= n) return;
  int start = row_start[wid], end = row_start[wid + 1];
  int deg = end - start;

  float adv[H];
#pragma unroll
  for (int hh = 0; hh < H; hh++) adv[hh] = a_d[wid * H + hh];

  if (deg <= 64) {
    // ---- pass 1: softmax weights, one edge per lane ----
    bool valid = lane < deg;
    int sn = valid ? edge_src[start + lane] : 0;
    float e[H];
    if (valid) {
      if constexpr (H == 4) {
        float4 asv = *(const float4*)(a_s + (size_t)sn * 4);
        float t0 = asv.x + adv[0];
        float t1 = asv.y + adv[1];
        float t2 = asv.z + adv[2];
        float t3 = asv.w + adv[3];
        e[0] = t0 >= 0.f ? t0 : SLOPE * t0;
        e[1] = t1 >= 0.f ? t1 : SLOPE * t1;
        e[2] = t2 >= 0.f ? t2 : SLOPE * t2;
        e[3] = t3 >= 0.f ? t3 : SLOPE * t3;
      } else {
        float t = a_s[sn] + adv[0];
        e[0] = t >= 0.f ? t : SLOPE * t;
      }
    } else {
#pragma unroll
      for (int hh = 0; hh < H; hh++) e[hh] = -1e30f;
    }
    float m[H], w[H], s[H];
#pragma unroll
    for (int hh = 0; hh < H; hh++) m[hh] = e[hh];
    for (int off = 1; off < 64; off <<= 1)
#pragma unroll
      for (int hh = 0; hh < H; hh++)
        m[hh] = fmaxf(m[hh], __shfl_xor(m[hh], off, 64));
#pragma unroll
    for (int hh = 0; hh < H; hh++) {
      w[hh] = __expf(e[hh] - m[hh]);  // invalid lanes -> exp(-huge) = 0
      s[hh] = w[hh];
    }
    for (int off = 1; off < 64; off <<= 1)
#pragma unroll
      for (int hh = 0; hh < H; hh++) s[hh] += __shfl_xor(s[hh], off, 64);
    sn_lds[wslot][lane] = sn;
#pragma unroll
    for (int hh = 0; hh < H; hh++)
      w_lds[wslot][hh * 66 + lane] = w[hh] * (1.f / s[hh]);
    __builtin_amdgcn_wave_barrier();

    // ---- pass 2: 4 edges in flight, 16 lanes x 8 dims each ----
    int g = lane >> 4, gl = lane & 15;
    int d0 = gl * 8;
    int head = d0 / C;
    float4 acc0 = {0.f, 0.f, 0.f, 0.f}, acc1 = {0.f, 0.f, 0.f, 0.f};
    for (int eidx = g; eidx < deg; eidx += 4) {
      int sn2 = sn_lds[wslot][eidx];
      float wv = w_lds[wslot][head * 66 + eidx];
      const float* hp = h + (size_t)sn2 * 128 + d0;
      float4 h0 = *(const float4*)hp;
      float4 h1 = *(const float4*)(hp + 4);
      acc0.x += wv * h0.x; acc0.y += wv * h0.y;
      acc0.z += wv * h0.z; acc0.w += wv * h0.w;
      acc1.x += wv * h1.x; acc1.y += wv * h1.y;
      acc1.z += wv * h1.z; acc1.w += wv * h1.w;
    }
    for (int off = 16; off < 64; off <<= 1) {
      acc0.x += __shfl_xor(acc0.x, off, 64);
      acc0.y += __shfl_xor(acc0.y, off, 64);
      acc0.z += __shfl_xor(acc0.z, off, 64);
      acc0.w += __shfl_xor(acc0.w, off, 64);
      acc1.x += __shfl_xor(acc1.x, off, 64);
      acc1.y += __shfl_xor(acc1.y, off, 64);
      acc1.z += __shfl_xor(acc1.z, off, 64);
      acc1.w += __shfl_xor(acc1.w, off, 64);
    }
    if (lane < 16) {
      float4 bv0 = *(const float4*)(bias + d0);
      float4 bv1 = *(const float4*)(bias + d0 + 4);
      float o[8] = {acc0.x + bv0.x, acc0.y + bv0.y, acc0.z + bv0.z,
                    acc0.w + bv0.w, acc1.x + bv1.x, acc1.y + bv1.y,
                    acc1.z + bv1.z, acc1.w + bv1.w};
      if (DO_ELU) {
#pragma unroll
        for (int i = 0; i < 8; i++) o[i] = (o[i] > 0.f) ? o[i] : __expf(o[i]) - 1.f;
      }
      float4 o0 = {o[0], o[1], o[2], o[3]};
      float4 o1 = {o[4], o[5], o[6], o[7]};
      *(float4*)(out + (size_t)wid * 128 + d0) = o0;
      *(float4*)(out + (size_t)wid * 128 + d0 + 4) = o1;
    }
    return;
  }

  // ---- generic fallback (deg > 64) — correctness only, ~never taken ----
  {
    const int G = C / 2;
    int head = lane / G;
    float m[H], s[H];
#pragma unroll
    for (int hh = 0; hh < H; hh++) { m[hh] = -1e30f; s[hh] = 0.f; }
    for (int idx = start + lane; idx < end; idx += 64) {
      int sn = edge_src[idx];
#pragma unroll
      for (int hh = 0; hh < H; hh++) {
        float e = a_s[sn * H + hh] + adv[hh];
        e = (e >= 0.f) ? e : SLOPE * e;
        float mn = fmaxf(m[hh], e);
        s[hh] = s[hh] * __expf(m[hh] - mn) + __expf(e - mn);
        m[hh] = mn;
      }
    }
    for (int off = 1; off < 64; off <<= 1) {
#pragma unroll
      for (int hh = 0; hh < H; hh++) {
        float mo = __shfl_xor(m[hh], off, 64);
        float so = __shfl_xor(s[hh], off, 64);
        float mn = fmaxf(m[hh], mo);
        s[hh] = s[hh] * __expf(m[hh] - mn) + so * __expf(mo - mn);
        m[hh] = mn;
      }
    }
    int d0 = lane * 2;
    float mh = m[head];
    float rsh = 1.f / s[head];
    float adh = adv[head];
    float acc0 = 0.f, acc1 = 0.f;
    for (int idx = start; idx < end; idx++) {
      int sn = edge_src[idx];
      float e = a_s[sn * H + head] + adh;
      e = (e >= 0.f) ? e : SLOPE * e;
      float w = __expf(e - mh) * rsh;
      float2 hv = *(const float2*)(h + (size_t)sn * 128 + d0);
      acc0 += w * hv.x;
      acc1 += w * hv.y;
    }
    float o0 = acc0 + bias[d0];
    float o1 = acc1 + bias[d0 + 1];
    if (DO_ELU) {
      o0 = (o0 > 0.f) ? o0 : __expf(o0) - 1.f;
      o1 = (o1 > 0.f) ? o1 : __expf(o1) - 1.f;
    }
    out[(size_t)wid * 128 + d0] = o0;
    out[(size_t)wid * 128 + d0 + 1] = o1;
  }
}

extern "C" void kernel_launch(void* const* d_in, const int* in_sizes, int n_in,
                              void* d_out, int out_size, void* d_ws,
                              size_t ws_size, hipStream_t stream) {
  const float* x = (const float*)d_in[0];
  const int* ei = (const int*)d_in[1];
  const float* W1 = (const float*)d_in[2];
  const float* as1 = (const float*)d_in[3];
  const float* ad1 = (const float*)d_in[4];
  const float* b1 = (const float*)d_in[5];
  const float* W2 = (const float*)d_in[6];
  const float* as2 = (const float*)d_in[7];
  const float* ad2 = (const float*)d_in[8];
  const float* b2 = (const float*)d_in[9];
  const float* W3 = (const float*)d_in[10];
  const float* as3 = (const float*)d_in[11];
  const float* ad3 = (const float*)d_in[12];
  const float* b3 = (const float*)d_in[13];
  float* out = (float*)d_out;

  const int n = N_NODES, E = N_EDGES, total = E + n;

  char* ws = (char*)d_ws;
  size_t off = 0;
  auto alloc = [&](size_t bytes) -> char* {
    char* p = ws + off;
    off = (off + bytes + 255) & ~(size_t)255;
    return p;
  };
  float* hbuf = (float*)alloc(sizeof(float) * (size_t)n * 128);  // 51.2 MB
  float* a_s = (float*)alloc(sizeof(float) * n * 4);
  float* a_d = (float*)alloc(sizeof(float) * n * 4);
  int* hist = (int*)alloc(sizeof(int) * n);
  int* incl = (int*)alloc(sizeof(int) * n);
  int* bsum = (int*)alloc(sizeof(int) * 256);
  int* row_start = (int*)alloc(sizeof(int) * (n + 1));
  int* cursor = (int*)alloc(sizeof(int) * n);
  int* edge_src = (int*)alloc(sizeof(int) * total);  // 6.8 MB

  hipMemsetAsync(hist, 0, sizeof(int) * n, stream);
  hipMemsetAsync(cursor, 0, sizeof(int) * n, stream);

  // CSR build (graph is shared by all 3 layers)
  hist_kernel<<<(total + 255) / 256, 256, 0, stream>>>(ei, hist, E, n);
  int nb = (n + SCAN_BLK - 1) / SCAN_BLK;  // 98
  scan_blocks<<<nb, 256, 0, stream>>>(hist, incl, bsum, n);
  scan_bsum<<<1, 128, 0, stream>>>(bsum, nb);
  finalize_rows<<<(n + 255) / 256, 256, 0, stream>>>(incl, bsum, row_start, n);
  scatter_kernel<<<(total + 255) / 256, 256, 0, stream>>>(ei, row_start, cursor,
                                                          edge_src, E, n);

  int agg_blocks = (n + 3) / 4;  // one wave per node, 4 waves/block

  // layer 1: x -> hbuf -> out (ELU)
  gemm128<<<n / 32, 256, 0, stream>>>(x, W1, hbuf, n);
  att_kernel<4><<<agg_blocks, 256, 0, stream>>>(hbuf, as1, ad1, a_s, a_d, n);
  agg_kernel<4, true><<<agg_blocks, 256, 0, stream>>>(
      hbuf, a_s, a_d, row_start, edge_src, b1, out, n);

  // layer 2: out -> hbuf -> out (ELU)
  gemm128<<<n / 32, 256, 0, stream>>>(out, W2, hbuf, n);
  att_kernel<4><<<agg_blocks, 256, 0, stream>>>(hbuf, as2, ad2, a_s, a_d, n);
  agg_kernel<4, true><<<agg_blocks, 256, 0, stream>>>(
      hbuf, a_s, a_d, row_start, edge_src, b2, out, n);

  // layer 3: out -> hbuf -> out (no ELU), heads=1
  gemm128<<<n / 32, 256, 0, stream>>>(out, W3, hbuf, n);
  att_kernel<1><<<agg_blocks, 256, 0, stream>>>(hbuf, as3, ad3, a_s, a_d, n);
  agg_kernel<1, false><<<agg_blocks, 256, 0, stream>>>(
      hbuf, a_s, a_d, row_start, edge_src, b3, out, n);
}

// Round 3
// 774.566 us; speedup vs baseline: 1.4949x; 1.2175x over previous
//
#include <hip/hip_runtime.h>
#include <hip/hip_fp16.h>
#include <math.h>

#define N_NODES 100000
#define N_EDGES 1600000
#define SLOPE 0.2f
#define SCAN_BLK 1024  // elements per scan block (256 threads * 4)

// ----------------- CSR build -----------------
__global__ void hist_kernel(const int* __restrict__ ei, int* __restrict__ hist,
                            int E, int n) {
  int e = blockIdx.x * blockDim.x + threadIdx.x;
  int total = E + n;
  if (e >= total) return;
  int d = (e < E) ? ei[E + e] : (e - E);
  atomicAdd(&hist[d], 1);
}

__global__ void scan_blocks(const int* __restrict__ in, int* __restrict__ incl,
                            int* __restrict__ bsum, int n) {
  __shared__ int lds[256];
  int t = threadIdx.x;
  int base = blockIdx.x * SCAN_BLK + t * 4;
  int v[4];
#pragma unroll
  for (int i = 0; i < 4; i++) v[i] = (base + i < n) ? in[base + i] : 0;
  v[1] += v[0]; v[2] += v[1]; v[3] += v[2];
  int x = v[3];
  lds[t] = x;
  __syncthreads();
  for (int off = 1; off < 256; off <<= 1) {
    int y = (t >= off) ? lds[t - off] : 0;
    __syncthreads();
    x += y;
    lds[t] = x;
    __syncthreads();
  }
  int excl = x - v[3];
#pragma unroll
  for (int i = 0; i < 4; i++)
    if (base + i < n) incl[base + i] = v[i] + excl;
  if (t == 255) bsum[blockIdx.x] = x;
}

__global__ void scan_bsum(int* bsum, int nb) {
  __shared__ int lds[128];
  int t = threadIdx.x;
  int orig = (t < nb) ? bsum[t] : 0;
  int x = orig;
  lds[t] = x;
  __syncthreads();
  for (int off = 1; off < 128; off <<= 1) {
    int y = (t >= off) ? lds[t - off] : 0;
    __syncthreads();
    x += y;
    lds[t] = x;
    __syncthreads();
  }
  if (t < nb) bsum[t] = x - orig;  // exclusive block offsets
}

__global__ void finalize_rows(const int* __restrict__ incl,
                              const int* __restrict__ bsum,
                              int* __restrict__ row_start, int n) {
  int i = blockIdx.x * blockDim.x + threadIdx.x;
  if (i < n) row_start[i + 1] = incl[i] + bsum[i / SCAN_BLK];
  if (i == 0) row_start[0] = 0;
}

__global__ void scatter_kernel(const int* __restrict__ ei,
                               const int* __restrict__ row_start,
                               int* __restrict__ cursor,
                               int* __restrict__ edge_src, int E, int n) {
  int e = blockIdx.x * blockDim.x + threadIdx.x;
  int total = E + n;
  if (e >= total) return;
  int s, d;
  if (e < E) { s = ei[e]; d = ei[E + e]; } else { s = e - E; d = e - E; }
  int pos = row_start[d] + atomicAdd(&cursor[d], 1);
  edge_src[pos] = s;
}

// ---- GEMM [n,128]x[128,128] fp32 -> fp16 h, fused attention dots ----
template <int H>
__global__ __launch_bounds__(256) void gemm_att(
    const float* __restrict__ X, const float* __restrict__ W,
    const float* __restrict__ att_src, const float* __restrict__ att_dst,
    __half* __restrict__ Y, float* __restrict__ a_s, float* __restrict__ a_d,
    int n) {
  __shared__ float xs[32 * 128];
  int t = threadIdx.x;
  int rowBase = blockIdx.x * 32;
  const float4* Xv = (const float4*)(X + (size_t)rowBase * 128);
  float4* xsv = (float4*)xs;
#pragma unroll
  for (int i = 0; i < 4; i++) xsv[t + i * 256] = Xv[t + i * 256];
  __syncthreads();
  int tx = t & 31, ty = t >> 5;
  float acc[4][4] = {};
  const float* Wc = W + tx * 4;
  for (int k = 0; k < 128; k += 4) {
    float4 w0 = *(const float4*)(Wc + (k + 0) * 128);
    float4 w1 = *(const float4*)(Wc + (k + 1) * 128);
    float4 w2 = *(const float4*)(Wc + (k + 2) * 128);
    float4 w3 = *(const float4*)(Wc + (k + 3) * 128);
#pragma unroll
    for (int r = 0; r < 4; r++) {
      int row = ty + r * 8;
      float4 xv = *(const float4*)(xs + row * 128 + k);
      acc[r][0] += xv.x * w0.x + xv.y * w1.x + xv.z * w2.x + xv.w * w3.x;
      acc[r][1] += xv.x * w0.y + xv.y * w1.y + xv.z * w2.y + xv.w * w3.y;
      acc[r][2] += xv.x * w0.z + xv.y * w1.z + xv.z * w2.z + xv.w * w3.z;
      acc[r][3] += xv.x * w0.w + xv.y * w1.w + xv.z * w2.w + xv.w * w3.w;
    }
  }
  // epilogue: fp16 store + fused attention dots
  float4 avs = *(const float4*)(att_src + tx * 4);
  float4 avd = *(const float4*)(att_dst + tx * 4);
#pragma unroll
  for (int r = 0; r < 4; r++) {
    int row = rowBase + ty + r * 8;
    union { float2 f; __half2 h2[2]; } u;
    u.h2[0] = __floats2half2_rn(acc[r][0], acc[r][1]);
    u.h2[1] = __floats2half2_rn(acc[r][2], acc[r][3]);
    *(float2*)(Y + (size_t)row * 128 + tx * 4) = u.f;
    float ps = acc[r][0] * avs.x + acc[r][1] * avs.y + acc[r][2] * avs.z +
               acc[r][3] * avs.w;
    float pd = acc[r][0] * avd.x + acc[r][1] * avd.y + acc[r][2] * avd.z +
               acc[r][3] * avd.w;
    const int RED = (H == 4) ? 4 : 16;  // 8-lane groups per head, or 32 lanes
#pragma unroll
    for (int off = 1; off <= RED; off <<= 1) {
      ps += __shfl_xor(ps, off, 64);
      pd += __shfl_xor(pd, off, 64);
    }
    if constexpr (H == 4) {
      if ((tx & 7) == 0) {
        a_s[row * 4 + (tx >> 3)] = ps;
        a_d[row * 4 + (tx >> 3)] = pd;
      }
    } else {
      if (tx == 0) {
        a_s[row] = ps;
        a_d[row] = pd;
      }
    }
  }
}

// ----------------- softmax + aggregation, one wave per dst node ----------
// Fast path (deg <= 64): one edge per lane; max-butterfly -> single exp ->
// sum-butterfly; normalized weights + src ids cached in LDS; then 8 edges
// in flight (8 lanes x 16 dims each, fp16 gather) for the accumulate.
template <int H, bool DO_ELU>
__global__ __launch_bounds__(256) void agg_kernel(
    const __half* __restrict__ h, const float* __restrict__ a_s,
    const float* __restrict__ a_d, const int* __restrict__ row_start,
    const int* __restrict__ edge_src, const float* __restrict__ bias,
    float* __restrict__ out, int n) {
  const int C = 128 / H;
  __shared__ float w_lds[4][H * 66];
  __shared__ int sn_lds[4][64];
  int wslot = threadIdx.x >> 6;
  int wid = (blockIdx.x * blockDim.x + threadIdx.x) >> 6;
  int lane = threadIdx.x & 63;
  if (wid >= n) return;
  int start = row_start[wid], end = row_start[wid + 1];
  int deg = end - start;

  float adv[H];
#pragma unroll
  for (int hh = 0; hh < H; hh++) adv[hh] = a_d[wid * H + hh];

  if (deg <= 64) {
    // ---- pass 1: softmax weights, one edge per lane ----
    bool valid = lane < deg;
    int sn = valid ? edge_src[start + lane] : 0;
    float e[H];
    if (valid) {
      if constexpr (H == 4) {
        float4 asv = *(const float4*)(a_s + (size_t)sn * 4);
        float t0 = asv.x + adv[0];
        float t1 = asv.y + adv[1];
        float t2 = asv.z + adv[2];
        float t3 = asv.w + adv[3];
        e[0] = t0 >= 0.f ? t0 : SLOPE * t0;
        e[1] = t1 >= 0.f ? t1 : SLOPE * t1;
        e[2] = t2 >= 0.f ? t2 : SLOPE * t2;
        e[3] = t3 >= 0.f ? t3 : SLOPE * t3;
      } else {
        float t = a_s[sn] + adv[0];
        e[0] = t >= 0.f ? t : SLOPE * t;
      }
    } else {
#pragma unroll
      for (int hh = 0; hh < H; hh++) e[hh] = -1e30f;
    }
    float m[H], w[H], s[H];
#pragma unroll
    for (int hh = 0; hh < H; hh++) m[hh] = e[hh];
    for (int off = 1; off < 64; off <<= 1)
#pragma unroll
      for (int hh = 0; hh < H; hh++)
        m[hh] = fmaxf(m[hh], __shfl_xor(m[hh], off, 64));
#pragma unroll
    for (int hh = 0; hh < H; hh++) {
      w[hh] = __expf(e[hh] - m[hh]);  // invalid lanes -> exp(-huge) = 0
      s[hh] = w[hh];
    }
    for (int off = 1; off < 64; off <<= 1)
#pragma unroll
      for (int hh = 0; hh < H; hh++) s[hh] += __shfl_xor(s[hh], off, 64);
    sn_lds[wslot][lane] = sn;
#pragma unroll
    for (int hh = 0; hh < H; hh++)
      w_lds[wslot][hh * 66 + lane] = w[hh] * (1.f / s[hh]);
    __builtin_amdgcn_wave_barrier();

    // ---- pass 2: 8 edges in flight, 8 lanes x 16 dims each (fp16) ----
    int g = lane >> 3, gl = lane & 7;
    int d0 = gl * 16;
    int head = d0 / C;
    float acc[16];
#pragma unroll
    for (int i = 0; i < 16; i++) acc[i] = 0.f;
    for (int eidx = g; eidx < deg; eidx += 8) {
      int sn2 = sn_lds[wslot][eidx];
      float wv = w_lds[wslot][head * 66 + eidx];
      const __half* hp = h + (size_t)sn2 * 128 + d0;
      union { float4 f; __half2 h2[4]; } u0, u1;
      u0.f = *(const float4*)hp;
      u1.f = *(const float4*)(hp + 8);
#pragma unroll
      for (int i = 0; i < 4; i++) {
        float2 a = __half22float2(u0.h2[i]);
        float2 b = __half22float2(u1.h2[i]);
        acc[2 * i] += wv * a.x;
        acc[2 * i + 1] += wv * a.y;
        acc[8 + 2 * i] += wv * b.x;
        acc[8 + 2 * i + 1] += wv * b.y;
      }
    }
    for (int off = 8; off < 64; off <<= 1)
#pragma unroll
      for (int i = 0; i < 16; i++) acc[i] += __shfl_xor(acc[i], off, 64);
    if (lane < 8) {
      float o[16];
#pragma unroll
      for (int q = 0; q < 4; q++) {
        float4 bv = *(const float4*)(bias + d0 + q * 4);
        o[4 * q + 0] = acc[4 * q + 0] + bv.x;
        o[4 * q + 1] = acc[4 * q + 1] + bv.y;
        o[4 * q + 2] = acc[4 * q + 2] + bv.z;
        o[4 * q + 3] = acc[4 * q + 3] + bv.w;
      }
      if (DO_ELU) {
#pragma unroll
        for (int i = 0; i < 16; i++)
          o[i] = (o[i] > 0.f) ? o[i] : __expf(o[i]) - 1.f;
      }
#pragma unroll
      for (int q = 0; q < 4; q++) {
        float4 ov = {o[4 * q], o[4 * q + 1], o[4 * q + 2], o[4 * q + 3]};
        *(float4*)(out + (size_t)wid * 128 + d0 + q * 4) = ov;
      }
    }
    return;
  }

  // ---- generic fallback (deg > 64) — correctness only, ~never taken ----
  {
    const int G = C / 2;
    int head = lane / G;
    float m[H], s[H];
#pragma unroll
    for (int hh = 0; hh < H; hh++) { m[hh] = -1e30f; s[hh] = 0.f; }
    for (int idx = start + lane; idx < end; idx += 64) {
      int sn = edge_src[idx];
#pragma unroll
      for (int hh = 0; hh < H; hh++) {
        float e = a_s[sn * H + hh] + adv[hh];
        e = (e >= 0.f) ? e : SLOPE * e;
        float mn = fmaxf(m[hh], e);
        s[hh] = s[hh] * __expf(m[hh] - mn) + __expf(e - mn);
        m[hh] = mn;
      }
    }
    for (int off = 1; off < 64; off <<= 1) {
#pragma unroll
      for (int hh = 0; hh < H; hh++) {
        float mo = __shfl_xor(m[hh], off, 64);
        float so = __shfl_xor(s[hh], off, 64);
        float mn = fmaxf(m[hh], mo);
        s[hh] = s[hh] * __expf(m[hh] - mn) + so * __expf(mo - mn);
        m[hh] = mn;
      }
    }
    int d0 = lane * 2;
    float mh = m[head];
    float rsh = 1.f / s[head];
    float adh = adv[head];
    float acc0 = 0.f, acc1 = 0.f;
    for (int idx = start; idx < end; idx++) {
      int sn = edge_src[idx];
      float e = a_s[sn * H + head] + adh;
      e = (e >= 0.f) ? e : SLOPE * e;
      float w = __expf(e - mh) * rsh;
      float2 hv = __half22float2(*(const __half2*)(h + (size_t)sn * 128 + d0));
      acc0 += w * hv.x;
      acc1 += w * hv.y;
    }
    float o0 = acc0 + bias[d0];
    float o1 = acc1 + bias[d0 + 1];
    if (DO_ELU) {
      o0 = (o0 > 0.f) ? o0 : __expf(o0) - 1.f;
      o1 = (o1 > 0.f) ? o1 : __expf(o1) - 1.f;
    }
    out[(size_t)wid * 128 + d0] = o0;
    out[(size_t)wid * 128 + d0 + 1] = o1;
  }
}

extern "C" void kernel_launch(void* const* d_in, const int* in_sizes, int n_in,
                              void* d_out, int out_size, void* d_ws,
                              size_t ws_size, hipStream_t stream) {
  const float* x = (const float*)d_in[0];
  const int* ei = (const int*)d_in[1];
  const float* W1 = (const float*)d_in[2];
  const float* as1 = (const float*)d_in[3];
  const float* ad1 = (const float*)d_in[4];
  const float* b1 = (const float*)d_in[5];
  const float* W2 = (const float*)d_in[6];
  const float* as2 = (const float*)d_in[7];
  const float* ad2 = (const float*)d_in[8];
  const float* b2 = (const float*)d_in[9];
  const float* W3 = (const float*)d_in[10];
  const float* as3 = (const float*)d_in[11];
  const float* ad3 = (const float*)d_in[12];
  const float* b3 = (const float*)d_in[13];
  float* out = (float*)d_out;

  const int n = N_NODES, E = N_EDGES, total = E + n;

  char* ws = (char*)d_ws;
  size_t off = 0;
  auto alloc = [&](size_t bytes) -> char* {
    char* p = ws + off;
    off = (off + bytes + 255) & ~(size_t)255;
    return p;
  };
  __half* hbuf = (__half*)alloc(sizeof(__half) * (size_t)n * 128);  // 25.6 MB
  float* a_s = (float*)alloc(sizeof(float) * n * 4);
  float* a_d = (float*)alloc(sizeof(float) * n * 4);
  int* hist = (int*)alloc(sizeof(int) * n);
  int* incl = (int*)alloc(sizeof(int) * n);
  int* bsum = (int*)alloc(sizeof(int) * 256);
  int* row_start = (int*)alloc(sizeof(int) * (n + 1));
  int* cursor = (int*)alloc(sizeof(int) * n);
  int* edge_src = (int*)alloc(sizeof(int) * total);  // 6.8 MB

  hipMemsetAsync(hist, 0, sizeof(int) * n, stream);
  hipMemsetAsync(cursor, 0, sizeof(int) * n, stream);

  // CSR build (graph is shared by all 3 layers)
  hist_kernel<<<(total + 255) / 256, 256, 0, stream>>>(ei, hist, E, n);
  int nb = (n + SCAN_BLK - 1) / SCAN_BLK;  // 98
  scan_blocks<<<nb, 256, 0, stream>>>(hist, incl, bsum, n);
  scan_bsum<<<1, 128, 0, stream>>>(bsum, nb);
  finalize_rows<<<(n + 255) / 256, 256, 0, stream>>>(incl, bsum, row_start, n);
  scatter_kernel<<<(total + 255) / 256, 256, 0, stream>>>(ei, row_start, cursor,
                                                          edge_src, E, n);

  int agg_blocks = (n + 3) / 4;  // one wave per node, 4 waves/block

  // layer 1: x -> hbuf(+dots) -> out (ELU)
  gemm_att<4><<<n / 32, 256, 0, stream>>>(x, W1, as1, ad1, hbuf, a_s, a_d, n);
  agg_kernel<4, true><<<agg_blocks, 256, 0, stream>>>(
      hbuf, a_s, a_d, row_start, edge_src, b1, out, n);

  // layer 2: out -> hbuf(+dots) -> out (ELU)
  gemm_att<4><<<n / 32, 256, 0, stream>>>(out, W2, as2, ad2, hbuf, a_s, a_d, n);
  agg_kernel<4, true><<<agg_blocks, 256, 0, stream>>>(
      hbuf, a_s, a_d, row_start, edge_src, b2, out, n);

  // layer 3: out -> hbuf(+dots) -> out (no ELU), heads=1
  gemm_att<1><<<n / 32, 256, 0, stream>>>(out, W3, as3, ad3, hbuf, a_s, a_d, n);
  agg_kernel<1, false><<<agg_blocks, 256, 0, stream>>>(
      hbuf, a_s, a_d, row_start, edge_src, b3, out, n);
}

// Round 4
// 666.588 us; speedup vs baseline: 1.7371x; 1.1620x over previous
//
#include <hip/hip_runtime.h>
#include <hip/hip_fp16.h>
#include <math.h>

#define N_NODES 100000
#define N_EDGES 1600000
#define SLOPE 0.2f

// ---- counting-sort CSR build parameters ----
#define BSHIFT 8                      // 256 nodes per bucket
#define NB 391                        // ceil(100000/256)
#define CHUNK 8192                    // edges per partition block

// ----------------- CSR build: two-level LDS counting sort -----------------
// Pass A1: per-block LDS histogram over NB buckets -> global bucket_count
__global__ __launch_bounds__(256) void partA1(const int* __restrict__ ei,
                                              int* __restrict__ bucket_count,
                                              int E, int n) {
  __shared__ int cnt[NB];
  for (int i = threadIdx.x; i < NB; i += 256) cnt[i] = 0;
  __syncthreads();
  int base = blockIdx.x * CHUNK;
  int total = E + n;
  int lim = min(base + CHUNK, total);
  for (int e = base + threadIdx.x; e < lim; e += 256) {
    int d = (e < E) ? ei[E + e] : (e - E);
    atomicAdd(&cnt[d >> BSHIFT], 1);
  }
  __syncthreads();
  for (int i = threadIdx.x; i < NB; i += 256)
    if (cnt[i]) atomicAdd(&bucket_count[i], cnt[i]);
}

// scan bucket counts -> bucket_base[NB+1], init bucket_cursor
__global__ __launch_bounds__(512) void scan_nb(
    const int* __restrict__ bucket_count, int* __restrict__ bucket_base,
    int* __restrict__ bucket_cursor) {
  __shared__ int lds[512];
  int t = threadIdx.x;
  int v = (t < NB) ? bucket_count[t] : 0;
  int x = v;
  lds[t] = x;
  __syncthreads();
  for (int off = 1; off < 512; off <<= 1) {
    int y = (t >= off) ? lds[t - off] : 0;
    __syncthreads();
    x += y;
    lds[t] = x;
    __syncthreads();
  }
  int excl = x - v;
  if (t <= NB) bucket_base[t] = excl;
  if (t < NB) bucket_cursor[t] = excl;
}

// Pass A2: re-histogram, reserve per-(block,bucket) windows with ONE global
// atomic each, then write packed (src<<8 | dst&255) into disjoint windows.
__global__ __launch_bounds__(256) void partA2(const int* __restrict__ ei,
                                              int* __restrict__ bucket_cursor,
                                              unsigned* __restrict__ part,
                                              int E, int n) {
  __shared__ int cnt[NB];
  __shared__ int res[NB];
  for (int i = threadIdx.x; i < NB; i += 256) cnt[i] = 0;
  __syncthreads();
  int base = blockIdx.x * CHUNK;
  int total = E + n;
  int lim = min(base + CHUNK, total);
  for (int e = base + threadIdx.x; e < lim; e += 256) {
    int d = (e < E) ? ei[E + e] : (e - E);
    atomicAdd(&cnt[d >> BSHIFT], 1);
  }
  __syncthreads();
  for (int i = threadIdx.x; i < NB; i += 256)
    res[i] = cnt[i] ? atomicAdd(&bucket_cursor[i], cnt[i]) : 0;
  __syncthreads();
  for (int e = base + threadIdx.x; e < lim; e += 256) {
    int s, d;
    if (e < E) { s = ei[e]; d = ei[E + e]; } else { s = d = e - E; }
    int b = d >> BSHIFT;
    int pos = atomicAdd(&res[b], 1);  // LDS atomic; res holds global cursor
    part[pos] = ((unsigned)s << BSHIFT) | (unsigned)(d & 255);
  }
}

// Pass B: one block per bucket; LDS count/scan/scatter -> row_start, edge_src
__global__ __launch_bounds__(256) void passB(const unsigned* __restrict__ part,
                                             const int* __restrict__ bucket_base,
                                             int* __restrict__ row_start,
                                             int* __restrict__ edge_src, int n) {
  __shared__ int cnt[256];
  __shared__ int sc[256];
  __shared__ int loff[256];
  int b = blockIdx.x;
  int t = threadIdx.x;
  int node0 = b << BSHIFT;
  int bstart = bucket_base[b], bend = bucket_base[b + 1];
  cnt[t] = 0;
  __syncthreads();
  for (int i = bstart + t; i < bend; i += 256)
    atomicAdd(&cnt[part[i] & 255], 1);
  __syncthreads();
  int v = cnt[t];
  int x = v;
  sc[t] = x;
  __syncthreads();
  for (int off = 1; off < 256; off <<= 1) {
    int y = (t >= off) ? sc[t - off] : 0;
    __syncthreads();
    x += y;
    sc[t] = x;
    __syncthreads();
  }
  int excl = x - v;
  loff[t] = excl;
  int node = node0 + t;
  if (node < n) row_start[node] = bstart + excl;
  if (b == NB - 1 && t == 0) row_start[n] = bucket_base[NB];
  __syncthreads();
  for (int i = bstart + t; i < bend; i += 256) {
    unsigned p = part[i];
    int dl = p & 255;
    int pos = bstart + atomicAdd(&loff[dl], 1);
    edge_src[pos] = (int)(p >> BSHIFT);
  }
}

// ---- GEMM [n,128]x[128,128] fp32 -> fp16 h, fused attention dots ----
template <int H>
__global__ __launch_bounds__(256) void gemm_att(
    const float* __restrict__ X, const float* __restrict__ W,
    const float* __restrict__ att_src, const float* __restrict__ att_dst,
    __half* __restrict__ Y, float* __restrict__ a_s, float* __restrict__ a_d,
    int n) {
  __shared__ float xs[32 * 128];
  int t = threadIdx.x;
  int rowBase = blockIdx.x * 32;
  const float4* Xv = (const float4*)(X + (size_t)rowBase * 128);
  float4* xsv = (float4*)xs;
#pragma unroll
  for (int i = 0; i < 4; i++) xsv[t + i * 256] = Xv[t + i * 256];
  __syncthreads();
  int tx = t & 31, ty = t >> 5;
  float acc[4][4] = {};
  const float* Wc = W + tx * 4;
  for (int k = 0; k < 128; k += 4) {
    float4 w0 = *(const float4*)(Wc + (k + 0) * 128);
    float4 w1 = *(const float4*)(Wc + (k + 1) * 128);
    float4 w2 = *(const float4*)(Wc + (k + 2) * 128);
    float4 w3 = *(const float4*)(Wc + (k + 3) * 128);
#pragma unroll
    for (int r = 0; r < 4; r++) {
      int row = ty + r * 8;
      float4 xv = *(const float4*)(xs + row * 128 + k);
      acc[r][0] += xv.x * w0.x + xv.y * w1.x + xv.z * w2.x + xv.w * w3.x;
      acc[r][1] += xv.x * w0.y + xv.y * w1.y + xv.z * w2.y + xv.w * w3.y;
      acc[r][2] += xv.x * w0.z + xv.y * w1.z + xv.z * w2.z + xv.w * w3.z;
      acc[r][3] += xv.x * w0.w + xv.y * w1.w + xv.z * w2.w + xv.w * w3.w;
    }
  }
  // epilogue: fp16 store + fused attention dots
  float4 avs = *(const float4*)(att_src + tx * 4);
  float4 avd = *(const float4*)(att_dst + tx * 4);
#pragma unroll
  for (int r = 0; r < 4; r++) {
    int row = rowBase + ty + r * 8;
    union { float2 f; __half2 h2[2]; } u;
    u.h2[0] = __floats2half2_rn(acc[r][0], acc[r][1]);
    u.h2[1] = __floats2half2_rn(acc[r][2], acc[r][3]);
    *(float2*)(Y + (size_t)row * 128 + tx * 4) = u.f;
    float ps = acc[r][0] * avs.x + acc[r][1] * avs.y + acc[r][2] * avs.z +
               acc[r][3] * avs.w;
    float pd = acc[r][0] * avd.x + acc[r][1] * avd.y + acc[r][2] * avd.z +
               acc[r][3] * avd.w;
    const int RED = (H == 4) ? 4 : 16;  // 8-lane groups per head, or 32 lanes
#pragma unroll
    for (int off = 1; off <= RED; off <<= 1) {
      ps += __shfl_xor(ps, off, 64);
      pd += __shfl_xor(pd, off, 64);
    }
    if constexpr (H == 4) {
      if ((tx & 7) == 0) {
        a_s[row * 4 + (tx >> 3)] = ps;
        a_d[row * 4 + (tx >> 3)] = pd;
      }
    } else {
      if (tx == 0) {
        a_s[row] = ps;
        a_d[row] = pd;
      }
    }
  }
}

// ----------------- softmax + aggregation, one wave per dst node ----------
template <int H, bool DO_ELU>
__global__ __launch_bounds__(256) void agg_kernel(
    const __half* __restrict__ h, const float* __restrict__ a_s,
    const float* __restrict__ a_d, const int* __restrict__ row_start,
    const int* __restrict__ edge_src, const float* __restrict__ bias,
    float* __restrict__ out, int n) {
  const int C = 128 / H;
  __shared__ float w_lds[4][H * 66];
  __shared__ int sn_lds[4][64];
  int wslot = threadIdx.x >> 6;
  int wid = (blockIdx.x * blockDim.x + threadIdx.x) >> 6;
  int lane = threadIdx.x & 63;
  if (wid >= n) return;
  int start = row_start[wid], end = row_start[wid + 1];
  int deg = end - start;

  float adv[H];
#pragma unroll
  for (int hh = 0; hh < H; hh++) adv[hh] = a_d[wid * H + hh];

  if (deg <= 64) {
    // ---- pass 1: softmax weights, one edge per lane ----
    bool valid = lane < deg;
    int sn = valid ? edge_src[start + lane] : 0;
    float e[H];
    if (valid) {
      if constexpr (H == 4) {
        float4 asv = *(const float4*)(a_s + (size_t)sn * 4);
        float t0 = asv.x + adv[0];
        float t1 = asv.y + adv[1];
        float t2 = asv.z + adv[2];
        float t3 = asv.w + adv[3];
        e[0] = t0 >= 0.f ? t0 : SLOPE * t0;
        e[1] = t1 >= 0.f ? t1 : SLOPE * t1;
        e[2] = t2 >= 0.f ? t2 : SLOPE * t2;
        e[3] = t3 >= 0.f ? t3 : SLOPE * t3;
      } else {
        float t = a_s[sn] + adv[0];
        e[0] = t >= 0.f ? t : SLOPE * t;
      }
    } else {
#pragma unroll
      for (int hh = 0; hh < H; hh++) e[hh] = -1e30f;
    }
    float m[H], w[H], s[H];
#pragma unroll
    for (int hh = 0; hh < H; hh++) m[hh] = e[hh];
    for (int off = 1; off < 64; off <<= 1)
#pragma unroll
      for (int hh = 0; hh < H; hh++)
        m[hh] = fmaxf(m[hh], __shfl_xor(m[hh], off, 64));
#pragma unroll
    for (int hh = 0; hh < H; hh++) {
      w[hh] = __expf(e[hh] - m[hh]);  // invalid lanes -> exp(-huge) = 0
      s[hh] = w[hh];
    }
    for (int off = 1; off < 64; off <<= 1)
#pragma unroll
      for (int hh = 0; hh < H; hh++) s[hh] += __shfl_xor(s[hh], off, 64);
    sn_lds[wslot][lane] = sn;
#pragma unroll
    for (int hh = 0; hh < H; hh++)
      w_lds[wslot][hh * 66 + lane] = w[hh] * (1.f / s[hh]);
    __builtin_amdgcn_wave_barrier();

    // ---- pass 2: 8 edges in flight, 8 lanes x 16 dims each (fp16) ----
    int g = lane >> 3, gl = lane & 7;
    int d0 = gl * 16;
    int head = d0 / C;
    float acc[16];
#pragma unroll
    for (int i = 0; i < 16; i++) acc[i] = 0.f;
    for (int eidx = g; eidx < deg; eidx += 8) {
      int sn2 = sn_lds[wslot][eidx];
      float wv = w_lds[wslot][head * 66 + eidx];
      const __half* hp = h + (size_t)sn2 * 128 + d0;
      union { float4 f; __half2 h2[4]; } u0, u1;
      u0.f = *(const float4*)hp;
      u1.f = *(const float4*)(hp + 8);
#pragma unroll
      for (int i = 0; i < 4; i++) {
        float2 a = __half22float2(u0.h2[i]);
        float2 b = __half22float2(u1.h2[i]);
        acc[2 * i] += wv * a.x;
        acc[2 * i + 1] += wv * a.y;
        acc[8 + 2 * i] += wv * b.x;
        acc[8 + 2 * i + 1] += wv * b.y;
      }
    }
    for (int off = 8; off < 64; off <<= 1)
#pragma unroll
      for (int i = 0; i < 16; i++) acc[i] += __shfl_xor(acc[i], off, 64);
    if (lane < 8) {
      float o[16];
#pragma unroll
      for (int q = 0; q < 4; q++) {
        float4 bv = *(const float4*)(bias + d0 + q * 4);
        o[4 * q + 0] = acc[4 * q + 0] + bv.x;
        o[4 * q + 1] = acc[4 * q + 1] + bv.y;
        o[4 * q + 2] = acc[4 * q + 2] + bv.z;
        o[4 * q + 3] = acc[4 * q + 3] + bv.w;
      }
      if (DO_ELU) {
#pragma unroll
        for (int i = 0; i < 16; i++)
          o[i] = (o[i] > 0.f) ? o[i] : __expf(o[i]) - 1.f;
      }
#pragma unroll
      for (int q = 0; q < 4; q++) {
        float4 ov = {o[4 * q], o[4 * q + 1], o[4 * q + 2], o[4 * q + 3]};
        *(float4*)(out + (size_t)wid * 128 + d0 + q * 4) = ov;
      }
    }
    return;
  }

  // ---- generic fallback (deg > 64) — correctness only, ~never taken ----
  {
    const int G = C / 2;
    int head = lane / G;
    float m[H], s[H];
#pragma unroll
    for (int hh = 0; hh < H; hh++) { m[hh] = -1e30f; s[hh] = 0.f; }
    for (int idx = start + lane; idx < end; idx += 64) {
      int sn = edge_src[idx];
#pragma unroll
      for (int hh = 0; hh < H; hh++) {
        float e = a_s[sn * H + hh] + adv[hh];
        e = (e >= 0.f) ? e : SLOPE * e;
        float mn = fmaxf(m[hh], e);
        s[hh] = s[hh] * __expf(m[hh] - mn) + __expf(e - mn);
        m[hh] = mn;
      }
    }
    for (int off = 1; off < 64; off <<= 1) {
#pragma unroll
      for (int hh = 0; hh < H; hh++) {
        float mo = __shfl_xor(m[hh], off, 64);
        float so = __shfl_xor(s[hh], off, 64);
        float mn = fmaxf(m[hh], mo);
        s[hh] = s[hh] * __expf(m[hh] - mn) + so * __expf(mo - mn);
        m[hh] = mn;
      }
    }
    int d0 = lane * 2;
    float mh = m[head];
    float rsh = 1.f / s[head];
    float adh = adv[head];
    float acc0 = 0.f, acc1 = 0.f;
    for (int idx = start; idx < end; idx++) {
      int sn = edge_src[idx];
      float e = a_s[sn * H + head] + adh;
      e = (e >= 0.f) ? e : SLOPE * e;
      float w = __expf(e - mh) * rsh;
      float2 hv = __half22float2(*(const __half2*)(h + (size_t)sn * 128 + d0));
      acc0 += w * hv.x;
      acc1 += w * hv.y;
    }
    float o0 = acc0 + bias[d0];
    float o1 = acc1 + bias[d0 + 1];
    if (DO_ELU) {
      o0 = (o0 > 0.f) ? o0 : __expf(o0) - 1.f;
      o1 = (o1 > 0.f) ? o1 : __expf(o1) - 1.f;
    }
    out[(size_t)wid * 128 + d0] = o0;
    out[(size_t)wid * 128 + d0 + 1] = o1;
  }
}

extern "C" void kernel_launch(void* const* d_in, const int* in_sizes, int n_in,
                              void* d_out, int out_size, void* d_ws,
                              size_t ws_size, hipStream_t stream) {
  const float* x = (const float*)d_in[0];
  const int* ei = (const int*)d_in[1];
  const float* W1 = (const float*)d_in[2];
  const float* as1 = (const float*)d_in[3];
  const float* ad1 = (const float*)d_in[4];
  const float* b1 = (const float*)d_in[5];
  const float* W2 = (const float*)d_in[6];
  const float* as2 = (const float*)d_in[7];
  const float* ad2 = (const float*)d_in[8];
  const float* b2 = (const float*)d_in[9];
  const float* W3 = (const float*)d_in[10];
  const float* as3 = (const float*)d_in[11];
  const float* ad3 = (const float*)d_in[12];
  const float* b3 = (const float*)d_in[13];
  float* out = (float*)d_out;

  const int n = N_NODES, E = N_EDGES, total = E + n;

  char* ws = (char*)d_ws;
  size_t off = 0;
  auto alloc = [&](size_t bytes) -> char* {
    char* p = ws + off;
    off = (off + bytes + 255) & ~(size_t)255;
    return p;
  };
  __half* hbuf = (__half*)alloc(sizeof(__half) * (size_t)n * 128);  // 25.6 MB
  float* a_s = (float*)alloc(sizeof(float) * n * 4);
  float* a_d = (float*)alloc(sizeof(float) * n * 4);
  unsigned* part = (unsigned*)alloc(sizeof(unsigned) * total);  // 6.8 MB
  int* edge_src = (int*)alloc(sizeof(int) * total);             // 6.8 MB
  int* row_start = (int*)alloc(sizeof(int) * (n + 1));
  int* bucket_count = (int*)alloc(sizeof(int) * (NB + 1));
  int* bucket_base = (int*)alloc(sizeof(int) * (NB + 1));
  int* bucket_cursor = (int*)alloc(sizeof(int) * (NB + 1));

  hipMemsetAsync(bucket_count, 0, sizeof(int) * (NB + 1), stream);

  // CSR build via two-level counting sort (graph shared by all 3 layers)
  int nblkA = (total + CHUNK - 1) / CHUNK;  // 208
  partA1<<<nblkA, 256, 0, stream>>>(ei, bucket_count, E, n);
  scan_nb<<<1, 512, 0, stream>>>(bucket_count, bucket_base, bucket_cursor);
  partA2<<<nblkA, 256, 0, stream>>>(ei, bucket_cursor, part, E, n);
  passB<<<NB, 256, 0, stream>>>(part, bucket_base, row_start, edge_src, n);

  int agg_blocks = (n + 3) / 4;  // one wave per node, 4 waves/block

  // layer 1: x -> hbuf(+dots) -> out (ELU)
  gemm_att<4><<<n / 32, 256, 0, stream>>>(x, W1, as1, ad1, hbuf, a_s, a_d, n);
  agg_kernel<4, true><<<agg_blocks, 256, 0, stream>>>(
      hbuf, a_s, a_d, row_start, edge_src, b1, out, n);

  // layer 2: out -> hbuf(+dots) -> out (ELU)
  gemm_att<4><<<n / 32, 256, 0, stream>>>(out, W2, as2, ad2, hbuf, a_s, a_d, n);
  agg_kernel<4, true><<<agg_blocks, 256, 0, stream>>>(
      hbuf, a_s, a_d, row_start, edge_src, b2, out, n);

  // layer 3: out -> hbuf(+dots) -> out (no ELU), heads=1
  gemm_att<1><<<n / 32, 256, 0, stream>>>(out, W3, as3, ad3, hbuf, a_s, a_d, n);
  agg_kernel<1, false><<<agg_blocks, 256, 0, stream>>>(
      hbuf, a_s, a_d, row_start, edge_src, b3, out, n);
}

// Round 5
// 599.422 us; speedup vs baseline: 1.9317x; 1.1121x over previous
//
#include <hip/hip_runtime.h>
#include <hip/hip_fp16.h>
#include <math.h>

#define N_NODES 100000
#define N_EDGES 1600000
#define SLOPE 0.2f

// ---- counting-sort CSR build parameters ----
#define BSHIFT 8                      // 256 nodes per bucket
#define NB 391                        // ceil(100000/256)
#define CHUNK 8192                    // edges per partition block

// ----------------- CSR build: two-level LDS counting sort -----------------
// Pass A1: per-block LDS histogram over NB buckets -> global bucket_count
__global__ __launch_bounds__(256) void partA1(const int* __restrict__ ei,
                                              int* __restrict__ bucket_count,
                                              int E, int n) {
  __shared__ int cnt[NB];
  for (int i = threadIdx.x; i < NB; i += 256) cnt[i] = 0;
  __syncthreads();
  int base = blockIdx.x * CHUNK;
  int total = E + n;
  int lim = min(base + CHUNK, total);
  for (int e = base + threadIdx.x; e < lim; e += 256) {
    int d = (e < E) ? ei[E + e] : (e - E);
    atomicAdd(&cnt[d >> BSHIFT], 1);
  }
  __syncthreads();
  for (int i = threadIdx.x; i < NB; i += 256)
    if (cnt[i]) atomicAdd(&bucket_count[i], cnt[i]);
}

// scan bucket counts -> bucket_base[NB+1], init bucket_cursor
__global__ __launch_bounds__(512) void scan_nb(
    const int* __restrict__ bucket_count, int* __restrict__ bucket_base,
    int* __restrict__ bucket_cursor) {
  __shared__ int lds[512];
  int t = threadIdx.x;
  int v = (t < NB) ? bucket_count[t] : 0;
  int x = v;
  lds[t] = x;
  __syncthreads();
  for (int off = 1; off < 512; off <<= 1) {
    int y = (t >= off) ? lds[t - off] : 0;
    __syncthreads();
    x += y;
    lds[t] = x;
    __syncthreads();
  }
  int excl = x - v;
  if (t <= NB) bucket_base[t] = excl;
  if (t < NB) bucket_cursor[t] = excl;
}

// Pass A2: re-histogram, reserve per-(block,bucket) windows with ONE global
// atomic each, then write packed (src<<8 | dst&255) into disjoint windows.
__global__ __launch_bounds__(256) void partA2(const int* __restrict__ ei,
                                              int* __restrict__ bucket_cursor,
                                              unsigned* __restrict__ part,
                                              int E, int n) {
  __shared__ int cnt[NB];
  __shared__ int res[NB];
  for (int i = threadIdx.x; i < NB; i += 256) cnt[i] = 0;
  __syncthreads();
  int base = blockIdx.x * CHUNK;
  int total = E + n;
  int lim = min(base + CHUNK, total);
  for (int e = base + threadIdx.x; e < lim; e += 256) {
    int d = (e < E) ? ei[E + e] : (e - E);
    atomicAdd(&cnt[d >> BSHIFT], 1);
  }
  __syncthreads();
  for (int i = threadIdx.x; i < NB; i += 256)
    res[i] = cnt[i] ? atomicAdd(&bucket_cursor[i], cnt[i]) : 0;
  __syncthreads();
  for (int e = base + threadIdx.x; e < lim; e += 256) {
    int s, d;
    if (e < E) { s = ei[e]; d = ei[E + e]; } else { s = d = e - E; }
    int b = d >> BSHIFT;
    int pos = atomicAdd(&res[b], 1);  // LDS atomic; res holds global cursor
    part[pos] = ((unsigned)s << BSHIFT) | (unsigned)(d & 255);
  }
}

// Pass B: one block per bucket; LDS count/scan/scatter -> row_start, edge_src
__global__ __launch_bounds__(256) void passB(const unsigned* __restrict__ part,
                                             const int* __restrict__ bucket_base,
                                             int* __restrict__ row_start,
                                             int* __restrict__ edge_src, int n) {
  __shared__ int cnt[256];
  __shared__ int sc[256];
  __shared__ int loff[256];
  int b = blockIdx.x;
  int t = threadIdx.x;
  int node0 = b << BSHIFT;
  int bstart = bucket_base[b], bend = bucket_base[b + 1];
  cnt[t] = 0;
  __syncthreads();
  for (int i = bstart + t; i < bend; i += 256)
    atomicAdd(&cnt[part[i] & 255], 1);
  __syncthreads();
  int v = cnt[t];
  int x = v;
  sc[t] = x;
  __syncthreads();
  for (int off = 1; off < 256; off <<= 1) {
    int y = (t >= off) ? sc[t - off] : 0;
    __syncthreads();
    x += y;
    sc[t] = x;
    __syncthreads();
  }
  int excl = x - v;
  loff[t] = excl;
  int node = node0 + t;
  if (node < n) row_start[node] = bstart + excl;
  if (b == NB - 1 && t == 0) row_start[n] = bucket_base[NB];
  __syncthreads();
  for (int i = bstart + t; i < bend; i += 256) {
    unsigned p = part[i];
    int dl = p & 255;
    int pos = bstart + atomicAdd(&loff[dl], 1);
    edge_src[pos] = (int)(p >> BSHIFT);
  }
}

// ---- GEMM [n,128]x[128,128] fp32 -> fp16 h, fused attention dots ----
template <int H>
__global__ __launch_bounds__(256) void gemm_att(
    const float* __restrict__ X, const float* __restrict__ W,
    const float* __restrict__ att_src, const float* __restrict__ att_dst,
    __half* __restrict__ Y, float* __restrict__ a_s, float* __restrict__ a_d,
    int n) {
  __shared__ float xs[32 * 128];
  int t = threadIdx.x;
  int rowBase = blockIdx.x * 32;
  const float4* Xv = (const float4*)(X + (size_t)rowBase * 128);
  float4* xsv = (float4*)xs;
#pragma unroll
  for (int i = 0; i < 4; i++) xsv[t + i * 256] = Xv[t + i * 256];
  __syncthreads();
  int tx = t & 31, ty = t >> 5;
  float acc[4][4] = {};
  const float* Wc = W + tx * 4;
  for (int k = 0; k < 128; k += 4) {
    float4 w0 = *(const float4*)(Wc + (k + 0) * 128);
    float4 w1 = *(const float4*)(Wc + (k + 1) * 128);
    float4 w2 = *(const float4*)(Wc + (k + 2) * 128);
    float4 w3 = *(const float4*)(Wc + (k + 3) * 128);
#pragma unroll
    for (int r = 0; r < 4; r++) {
      int row = ty + r * 8;
      float4 xv = *(const float4*)(xs + row * 128 + k);
      acc[r][0] += xv.x * w0.x + xv.y * w1.x + xv.z * w2.x + xv.w * w3.x;
      acc[r][1] += xv.x * w0.y + xv.y * w1.y + xv.z * w2.y + xv.w * w3.y;
      acc[r][2] += xv.x * w0.z + xv.y * w1.z + xv.z * w2.z + xv.w * w3.z;
      acc[r][3] += xv.x * w0.w + xv.y * w1.w + xv.z * w2.w + xv.w * w3.w;
    }
  }
  // epilogue: fp16 store + fused attention dots
  float4 avs = *(const float4*)(att_src + tx * 4);
  float4 avd = *(const float4*)(att_dst + tx * 4);
#pragma unroll
  for (int r = 0; r < 4; r++) {
    int row = rowBase + ty + r * 8;
    union { float2 f; __half2 h2[2]; } u;
    u.h2[0] = __floats2half2_rn(acc[r][0], acc[r][1]);
    u.h2[1] = __floats2half2_rn(acc[r][2], acc[r][3]);
    *(float2*)(Y + (size_t)row * 128 + tx * 4) = u.f;
    float ps = acc[r][0] * avs.x + acc[r][1] * avs.y + acc[r][2] * avs.z +
               acc[r][3] * avs.w;
    float pd = acc[r][0] * avd.x + acc[r][1] * avd.y + acc[r][2] * avd.z +
               acc[r][3] * avd.w;
    const int RED = (H == 4) ? 4 : 16;  // 8-lane groups per head, or 32 lanes
#pragma unroll
    for (int off = 1; off <= RED; off <<= 1) {
      ps += __shfl_xor(ps, off, 64);
      pd += __shfl_xor(pd, off, 64);
    }
    if constexpr (H == 4) {
      if ((tx & 7) == 0) {
        a_s[row * 4 + (tx >> 3)] = ps;
        a_d[row * 4 + (tx >> 3)] = pd;
      }
    } else {
      if (tx == 0) {
        a_s[row] = ps;
        a_d[row] = pd;
      }
    }
  }
}

// ----------------- softmax + aggregation, one wave per dst node ----------
// Fast path (deg <= 64): pass 1 = one edge per lane, max/sum butterflies
// (5 levels when deg<=32), normalized weights + src ids in LDS (zero-padded).
// Pass 2 = dim-parallel: each lane owns 2 dims, serial over edges with
// broadcast LDS weights; no final reduction, all lanes write the epilogue.
template <int H, bool DO_ELU>
__global__ __launch_bounds__(256) void agg_kernel(
    const __half* __restrict__ h, const float* __restrict__ a_s,
    const float* __restrict__ a_d, const int* __restrict__ row_start,
    const int* __restrict__ edge_src, const float* __restrict__ bias,
    float* __restrict__ out, int n) {
  const int C = 128 / H;
  __shared__ float w_lds[4][H * 66];
  __shared__ int sn_lds[4][64];
  int wslot = threadIdx.x >> 6;
  int wid = (blockIdx.x * blockDim.x + threadIdx.x) >> 6;
  int lane = threadIdx.x & 63;
  if (wid >= n) return;
  int start = row_start[wid], end = row_start[wid + 1];
  int deg = end - start;

  float adv[H];
#pragma unroll
  for (int hh = 0; hh < H; hh++) adv[hh] = a_d[wid * H + hh];

  if (deg <= 64) {
    // ---- pass 1: softmax weights, one edge per lane ----
    bool valid = lane < deg;
    int sn = valid ? edge_src[start + lane] : 0;
    float e[H];
    if (valid) {
      if constexpr (H == 4) {
        float4 asv = *(const float4*)(a_s + (size_t)sn * 4);
        float t0 = asv.x + adv[0];
        float t1 = asv.y + adv[1];
        float t2 = asv.z + adv[2];
        float t3 = asv.w + adv[3];
        e[0] = t0 >= 0.f ? t0 : SLOPE * t0;
        e[1] = t1 >= 0.f ? t1 : SLOPE * t1;
        e[2] = t2 >= 0.f ? t2 : SLOPE * t2;
        e[3] = t3 >= 0.f ? t3 : SLOPE * t3;
      } else {
        float t = a_s[sn] + adv[0];
        e[0] = t >= 0.f ? t : SLOPE * t;
      }
    } else {
#pragma unroll
      for (int hh = 0; hh < H; hh++) e[hh] = -1e30f;
    }
    bool small = (deg <= 32);
    float m[H], w[H], s[H];
#pragma unroll
    for (int hh = 0; hh < H; hh++) m[hh] = e[hh];
#pragma unroll
    for (int off = 1; off <= 16; off <<= 1)
#pragma unroll
      for (int hh = 0; hh < H; hh++)
        m[hh] = fmaxf(m[hh], __shfl_xor(m[hh], off, 64));
    if (!small)
#pragma unroll
      for (int hh = 0; hh < H; hh++)
        m[hh] = fmaxf(m[hh], __shfl_xor(m[hh], 32, 64));
#pragma unroll
    for (int hh = 0; hh < H; hh++) {
      w[hh] = valid ? __expf(e[hh] - m[hh]) : 0.f;
      s[hh] = w[hh];
    }
#pragma unroll
    for (int off = 1; off <= 16; off <<= 1)
#pragma unroll
      for (int hh = 0; hh < H; hh++) s[hh] += __shfl_xor(s[hh], off, 64);
    if (!small)
#pragma unroll
      for (int hh = 0; hh < H; hh++) s[hh] += __shfl_xor(s[hh], 32, 64);
    sn_lds[wslot][lane] = sn;
#pragma unroll
    for (int hh = 0; hh < H; hh++)
      w_lds[wslot][hh * 66 + lane] = valid ? w[hh] * (1.f / s[hh]) : 0.f;
    __builtin_amdgcn_wave_barrier();

    // ---- pass 2: dim-parallel, 2 dims per lane, serial over edges ----
    int d0 = lane * 2;
    int headBase = (H == 4) ? (lane >> 4) * 66 : 0;
    float acc0 = 0.f, acc1 = 0.f;
    int degp = (deg + 3) & ~3;  // pad slots have w=0, sn=0 (safe row)
    for (int eidx = 0; eidx < degp; eidx += 4) {
#pragma unroll
      for (int j = 0; j < 4; j++) {
        int sn2 = sn_lds[wslot][eidx + j];
        float wv = w_lds[wslot][headBase + eidx + j];
        __half2 hv = *(const __half2*)(h + (size_t)sn2 * 128 + d0);
        acc0 = fmaf(__half2float(hv.x), wv, acc0);
        acc1 = fmaf(__half2float(hv.y), wv, acc1);
      }
    }
    float2 bv = *(const float2*)(bias + d0);
    float o0 = acc0 + bv.x;
    float o1 = acc1 + bv.y;
    if (DO_ELU) {
      o0 = (o0 > 0.f) ? o0 : __expf(o0) - 1.f;
      o1 = (o1 > 0.f) ? o1 : __expf(o1) - 1.f;
    }
    float2 ov = {o0, o1};
    *(float2*)(out + (size_t)wid * 128 + d0) = ov;
    return;
  }

  // ---- generic fallback (deg > 64) — correctness only, ~never taken ----
  {
    const int G = C / 2;
    int head = lane / G;
    float m[H], s[H];
#pragma unroll
    for (int hh = 0; hh < H; hh++) { m[hh] = -1e30f; s[hh] = 0.f; }
    for (int idx = start + lane; idx < end; idx += 64) {
      int sn = edge_src[idx];
#pragma unroll
      for (int hh = 0; hh < H; hh++) {
        float e = a_s[sn * H + hh] + adv[hh];
        e = (e >= 0.f) ? e : SLOPE * e;
        float mn = fmaxf(m[hh], e);
        s[hh] = s[hh] * __expf(m[hh] - mn) + __expf(e - mn);
        m[hh] = mn;
      }
    }
    for (int off = 1; off < 64; off <<= 1) {
#pragma unroll
      for (int hh = 0; hh < H; hh++) {
        float mo = __shfl_xor(m[hh], off, 64);
        float so = __shfl_xor(s[hh], off, 64);
        float mn = fmaxf(m[hh], mo);
        s[hh] = s[hh] * __expf(m[hh] - mn) + so * __expf(mo - mn);
        m[hh] = mn;
      }
    }
    int d0 = lane * 2;
    float mh = m[head];
    float rsh = 1.f / s[head];
    float adh = adv[head];
    float acc0 = 0.f, acc1 = 0.f;
    for (int idx = start; idx < end; idx++) {
      int sn = edge_src[idx];
      float e = a_s[sn * H + head] + adh;
      e = (e >= 0.f) ? e : SLOPE * e;
      float w = __expf(e - mh) * rsh;
      float2 hv = __half22float2(*(const __half2*)(h + (size_t)sn * 128 + d0));
      acc0 += w * hv.x;
      acc1 += w * hv.y;
    }
    float o0 = acc0 + bias[d0];
    float o1 = acc1 + bias[d0 + 1];
    if (DO_ELU) {
      o0 = (o0 > 0.f) ? o0 : __expf(o0) - 1.f;
      o1 = (o1 > 0.f) ? o1 : __expf(o1) - 1.f;
    }
    out[(size_t)wid * 128 + d0] = o0;
    out[(size_t)wid * 128 + d0 + 1] = o1;
  }
}

extern "C" void kernel_launch(void* const* d_in, const int* in_sizes, int n_in,
                              void* d_out, int out_size, void* d_ws,
                              size_t ws_size, hipStream_t stream) {
  const float* x = (const float*)d_in[0];
  const int* ei = (const int*)d_in[1];
  const float* W1 = (const float*)d_in[2];
  const float* as1 = (const float*)d_in[3];
  const float* ad1 = (const float*)d_in[4];
  const float* b1 = (const float*)d_in[5];
  const float* W2 = (const float*)d_in[6];
  const float* as2 = (const float*)d_in[7];
  const float* ad2 = (const float*)d_in[8];
  const float* b2 = (const float*)d_in[9];
  const float* W3 = (const float*)d_in[10];
  const float* as3 = (const float*)d_in[11];
  const float* ad3 = (const float*)d_in[12];
  const float* b3 = (const float*)d_in[13];
  float* out = (float*)d_out;

  const int n = N_NODES, E = N_EDGES, total = E + n;

  char* ws = (char*)d_ws;
  size_t off = 0;
  auto alloc = [&](size_t bytes) -> char* {
    char* p = ws + off;
    off = (off + bytes + 255) & ~(size_t)255;
    return p;
  };
  __half* hbuf = (__half*)alloc(sizeof(__half) * (size_t)n * 128);  // 25.6 MB
  float* a_s = (float*)alloc(sizeof(float) * n * 4);
  float* a_d = (float*)alloc(sizeof(float) * n * 4);
  unsigned* part = (unsigned*)alloc(sizeof(unsigned) * total);  // 6.8 MB
  int* edge_src = (int*)alloc(sizeof(int) * total);             // 6.8 MB
  int* row_start = (int*)alloc(sizeof(int) * (n + 1));
  int* bucket_count = (int*)alloc(sizeof(int) * (NB + 1));
  int* bucket_base = (int*)alloc(sizeof(int) * (NB + 1));
  int* bucket_cursor = (int*)alloc(sizeof(int) * (NB + 1));

  hipMemsetAsync(bucket_count, 0, sizeof(int) * (NB + 1), stream);

  // CSR build via two-level counting sort (graph shared by all 3 layers)
  int nblkA = (total + CHUNK - 1) / CHUNK;  // 208
  partA1<<<nblkA, 256, 0, stream>>>(ei, bucket_count, E, n);
  scan_nb<<<1, 512, 0, stream>>>(bucket_count, bucket_base, bucket_cursor);
  partA2<<<nblkA, 256, 0, stream>>>(ei, bucket_cursor, part, E, n);
  passB<<<NB, 256, 0, stream>>>(part, bucket_base, row_start, edge_src, n);

  int agg_blocks = (n + 3) / 4;  // one wave per node, 4 waves/block

  // layer 1: x -> hbuf(+dots) -> out (ELU)
  gemm_att<4><<<n / 32, 256, 0, stream>>>(x, W1, as1, ad1, hbuf, a_s, a_d, n);
  agg_kernel<4, true><<<agg_blocks, 256, 0, stream>>>(
      hbuf, a_s, a_d, row_start, edge_src, b1, out, n);

  // layer 2: out -> hbuf(+dots) -> out (ELU)
  gemm_att<4><<<n / 32, 256, 0, stream>>>(out, W2, as2, ad2, hbuf, a_s, a_d, n);
  agg_kernel<4, true><<<agg_blocks, 256, 0, stream>>>(
      hbuf, a_s, a_d, row_start, edge_src, b2, out, n);

  // layer 3: out -> hbuf(+dots) -> out (no ELU), heads=1
  gemm_att<1><<<n / 32, 256, 0, stream>>>(out, W3, as3, ad3, hbuf, a_s, a_d, n);
  agg_kernel<1, false><<<agg_blocks, 256, 0, stream>>>(
      hbuf, a_s, a_d, row_start, edge_src, b3, out, n);
}

// Round 6
// 524.136 us; speedup vs baseline: 2.2092x; 1.1436x over previous
//
#include <hip/hip_runtime.h>
#include <hip/hip_fp16.h>
#include <math.h>

#define N_NODES 100000
#define N_EDGES 1600000
#define SLOPE 0.2f

// ---- counting-sort CSR build parameters ----
#define BSHIFT 8                      // 256 nodes per bucket
#define NB 391                        // ceil(100000/256)
#define CHUNK 8192                    // edges per partition block

typedef _Float16 f16x8 __attribute__((ext_vector_type(8)));
typedef float f32x4 __attribute__((ext_vector_type(4)));

// ----------------- CSR build: two-level LDS counting sort -----------------
__global__ __launch_bounds__(256) void partA1(const int* __restrict__ ei,
                                              int* __restrict__ bucket_count,
                                              int E, int n) {
  __shared__ int cnt[NB];
  for (int i = threadIdx.x; i < NB; i += 256) cnt[i] = 0;
  __syncthreads();
  int base = blockIdx.x * CHUNK;
  int total = E + n;
  int lim = min(base + CHUNK, total);
  for (int e = base + threadIdx.x; e < lim; e += 256) {
    int d = (e < E) ? ei[E + e] : (e - E);
    atomicAdd(&cnt[d >> BSHIFT], 1);
  }
  __syncthreads();
  for (int i = threadIdx.x; i < NB; i += 256)
    if (cnt[i]) atomicAdd(&bucket_count[i], cnt[i]);
}

__global__ __launch_bounds__(512) void scan_nb(
    const int* __restrict__ bucket_count, int* __restrict__ bucket_base,
    int* __restrict__ bucket_cursor) {
  __shared__ int lds[512];
  int t = threadIdx.x;
  int v = (t < NB) ? bucket_count[t] : 0;
  int x = v;
  lds[t] = x;
  __syncthreads();
  for (int off = 1; off < 512; off <<= 1) {
    int y = (t >= off) ? lds[t - off] : 0;
    __syncthreads();
    x += y;
    lds[t] = x;
    __syncthreads();
  }
  int excl = x - v;
  if (t <= NB) bucket_base[t] = excl;
  if (t < NB) bucket_cursor[t] = excl;
}

__global__ __launch_bounds__(256) void partA2(const int* __restrict__ ei,
                                              int* __restrict__ bucket_cursor,
                                              unsigned* __restrict__ part,
                                              int E, int n) {
  __shared__ int cnt[NB];
  __shared__ int res[NB];
  for (int i = threadIdx.x; i < NB; i += 256) cnt[i] = 0;
  __syncthreads();
  int base = blockIdx.x * CHUNK;
  int total = E + n;
  int lim = min(base + CHUNK, total);
  for (int e = base + threadIdx.x; e < lim; e += 256) {
    int d = (e < E) ? ei[E + e] : (e - E);
    atomicAdd(&cnt[d >> BSHIFT], 1);
  }
  __syncthreads();
  for (int i = threadIdx.x; i < NB; i += 256)
    res[i] = cnt[i] ? atomicAdd(&bucket_cursor[i], cnt[i]) : 0;
  __syncthreads();
  for (int e = base + threadIdx.x; e < lim; e += 256) {
    int s, d;
    if (e < E) { s = ei[e]; d = ei[E + e]; } else { s = d = e - E; }
    int b = d >> BSHIFT;
    int pos = atomicAdd(&res[b], 1);  // LDS atomic; res holds global cursor
    part[pos] = ((unsigned)s << BSHIFT) | (unsigned)(d & 255);
  }
}

__global__ __launch_bounds__(256) void passB(const unsigned* __restrict__ part,
                                             const int* __restrict__ bucket_base,
                                             int* __restrict__ row_start,
                                             int* __restrict__ edge_src, int n) {
  __shared__ int cnt[256];
  __shared__ int sc[256];
  __shared__ int loff[256];
  int b = blockIdx.x;
  int t = threadIdx.x;
  int node0 = b << BSHIFT;
  int bstart = bucket_base[b], bend = bucket_base[b + 1];
  cnt[t] = 0;
  __syncthreads();
  for (int i = bstart + t; i < bend; i += 256)
    atomicAdd(&cnt[part[i] & 255], 1);
  __syncthreads();
  int v = cnt[t];
  int x = v;
  sc[t] = x;
  __syncthreads();
  for (int off = 1; off < 256; off <<= 1) {
    int y = (t >= off) ? sc[t - off] : 0;
    __syncthreads();
    x += y;
    sc[t] = x;
    __syncthreads();
  }
  int excl = x - v;
  loff[t] = excl;
  int node = node0 + t;
  if (node < n) row_start[node] = bstart + excl;
  if (b == NB - 1 && t == 0) row_start[n] = bucket_base[NB];
  __syncthreads();
  for (int i = bstart + t; i < bend; i += 256) {
    unsigned p = part[i];
    int dl = p & 255;
    int pos = bstart + atomicAdd(&loff[dl], 1);
    edge_src[pos] = (int)(p >> BSHIFT);
  }
}

// ---- convert 3 weight matrices fp32 [k][col] -> fp16 transposed [col][k] ----
__global__ __launch_bounds__(256) void convert_w(
    const float* __restrict__ W1, const float* __restrict__ W2,
    const float* __restrict__ W3, __half* __restrict__ Wt1,
    __half* __restrict__ Wt2, __half* __restrict__ Wt3) {
  int idx = blockIdx.x * 256 + threadIdx.x;  // 3 * 16384
  if (idx >= 3 * 16384) return;
  int mat = idx >> 14;
  int r = idx & 16383;
  int k = r >> 7, col = r & 127;
  const float* W = (mat == 0) ? W1 : (mat == 1) ? W2 : W3;
  __half* Wt = (mat == 0) ? Wt1 : (mat == 1) ? Wt2 : Wt3;
  Wt[col * 128 + k] = __float2half(W[k * 128 + col]);
}

// ---- MFMA fp16 GEMM [n,128]x[128,128] + fused attention dots ----
// Block: 256 threads (4 waves), 64 rows. Wave w: rows [w*16, w*16+16).
// mfma_f32_16x16x32_f16, layouts (verified m89/m91/m120):
//   A[m][k]: m=lane&15, k=(lane>>4)*8+j ; B[k][nc]: nc=lane&15, k=(lane>>4)*8+j
//   D: col=lane&15, row=(lane>>4)*4+reg
template <int H>
__global__ __launch_bounds__(256) void gemm_att_mfma(
    const float* __restrict__ X, const __half* __restrict__ Wt,  // Wt[col][k]
    const float* __restrict__ att_src, const float* __restrict__ att_dst,
    __half* __restrict__ Y, float* __restrict__ a_s, float* __restrict__ a_d,
    int n) {
  __shared__ _Float16 A_lds[64 * 128];   // 16 KB
  __shared__ _Float16 B_lds[128 * 128];  // 32 KB
  int t = threadIdx.x;
  int r0 = blockIdx.x * 64;

  // stage A (fp32 -> fp16): thread t -> row t>>2, cols (t&3)*32..+32
  {
    int row = t >> 2;
    int c0 = (t & 3) * 32;
    const float* xp = X + (size_t)(r0 + row) * 128 + c0;
    bool inb = (r0 + row) < n;
#pragma unroll
    for (int i = 0; i < 8; i++) {
      float4 v;
      if (inb) v = *(const float4*)(xp + i * 4);
      else v = make_float4(0.f, 0.f, 0.f, 0.f);
      union { float2 f; __half2 h2[2]; } u;
      u.h2[0] = __floats2half2_rn(v.x, v.y);
      u.h2[1] = __floats2half2_rn(v.z, v.w);
      *(float2*)&A_lds[row * 128 + c0 + i * 4] = u.f;
    }
  }
  // stage B: thread t copies 64 halves (Wt already fp16 transposed)
  {
    const __half* wp = Wt + t * 64;
#pragma unroll
    for (int i = 0; i < 8; i++)
      *(float4*)&B_lds[t * 64 + i * 8] = *(const float4*)(wp + i * 8);
  }
  __syncthreads();

  int wv = t >> 6, lane = t & 63, quad = lane >> 4, l15 = lane & 15;
  const _Float16* Arow = &A_lds[(wv * 16 + l15) * 128];
  f32x4 acc[8];
#pragma unroll
  for (int ct = 0; ct < 8; ct++) acc[ct] = (f32x4){0.f, 0.f, 0.f, 0.f};

#pragma unroll
  for (int kb = 0; kb < 4; kb++) {
    f16x8 a = *(const f16x8*)(Arow + kb * 32 + quad * 8);
#pragma unroll
    for (int ct = 0; ct < 8; ct++) {
      f16x8 b = *(const f16x8*)(&B_lds[(ct * 16 + l15) * 128 + kb * 32 + quad * 8]);
      acc[ct] = __builtin_amdgcn_mfma_f32_16x16x32_f16(a, b, acc[ct], 0, 0, 0);
    }
  }

  int rbase = r0 + wv * 16 + quad * 4;
  // Y fp16 stores (64 lanes store contiguous 128B per (ct,reg))
#pragma unroll
  for (int reg = 0; reg < 4; reg++) {
    int row = rbase + reg;
    if (row < n) {
#pragma unroll
      for (int ct = 0; ct < 8; ct++)
        Y[(size_t)row * 128 + ct * 16 + l15] = __float2half(acc[ct][reg]);
    }
  }

  // fused attention dots
  float avs[8], avd[8];
#pragma unroll
  for (int ct = 0; ct < 8; ct++) {
    avs[ct] = att_src[ct * 16 + l15];
    avd[ct] = att_dst[ct * 16 + l15];
  }
  if constexpr (H == 4) {
    float ps[4][4], pd_[4][4];  // [head][reg]
#pragma unroll
    for (int hd = 0; hd < 4; hd++)
#pragma unroll
      for (int reg = 0; reg < 4; reg++) { ps[hd][reg] = 0.f; pd_[hd][reg] = 0.f; }
#pragma unroll
    for (int ct = 0; ct < 8; ct++) {
      int hd = ct >> 1;
#pragma unroll
      for (int reg = 0; reg < 4; reg++) {
        ps[hd][reg] = fmaf(acc[ct][reg], avs[ct], ps[hd][reg]);
        pd_[hd][reg] = fmaf(acc[ct][reg], avd[ct], pd_[hd][reg]);
      }
    }
#pragma unroll
    for (int off = 1; off <= 8; off <<= 1)
#pragma unroll
      for (int hd = 0; hd < 4; hd++)
#pragma unroll
        for (int reg = 0; reg < 4; reg++) {
          ps[hd][reg] += __shfl_xor(ps[hd][reg], off, 64);
          pd_[hd][reg] += __shfl_xor(pd_[hd][reg], off, 64);
        }
#pragma unroll
    for (int hd = 0; hd < 4; hd++)
      if (l15 == hd) {
#pragma unroll
        for (int reg = 0; reg < 4; reg++) {
          int row = rbase + reg;
          if (row < n) {
            a_s[row * 4 + hd] = ps[hd][reg];
            a_d[row * 4 + hd] = pd_[hd][reg];
          }
        }
      }
  } else {
    float ps[4] = {}, pd_[4] = {};
#pragma unroll
    for (int ct = 0; ct < 8; ct++)
#pragma unroll
      for (int reg = 0; reg < 4; reg++) {
        ps[reg] = fmaf(acc[ct][reg], avs[ct], ps[reg]);
        pd_[reg] = fmaf(acc[ct][reg], avd[ct], pd_[reg]);
      }
#pragma unroll
    for (int off = 1; off <= 8; off <<= 1)
#pragma unroll
      for (int reg = 0; reg < 4; reg++) {
        ps[reg] += __shfl_xor(ps[reg], off, 64);
        pd_[reg] += __shfl_xor(pd_[reg], off, 64);
      }
    if (l15 == 0) {
#pragma unroll
      for (int reg = 0; reg < 4; reg++) {
        int row = rbase + reg;
        if (row < n) { a_s[row] = ps[reg]; a_d[row] = pd_[reg]; }
      }
    }
  }
}

// ----------------- softmax + aggregation, one wave per dst node ----------
// Pass 1: one edge per lane, max/sum butterflies, normalized weights in LDS.
// Pass 2: 2 edges in flight (32 lanes x 4 dims, dwordx2 gathers), single
// shfl_xor(32) reduce, half-wave float4 store.
template <int H, bool DO_ELU>
__global__ __launch_bounds__(256) void agg_kernel(
    const __half* __restrict__ h, const float* __restrict__ a_s,
    const float* __restrict__ a_d, const int* __restrict__ row_start,
    const int* __restrict__ edge_src, const float* __restrict__ bias,
    float* __restrict__ out, int n) {
  const int C = 128 / H;
  __shared__ float w_lds[4][H * 66];
  __shared__ int sn_lds[4][64];
  int wslot = threadIdx.x >> 6;
  int wid = (blockIdx.x * blockDim.x + threadIdx.x) >> 6;
  int lane = threadIdx.x & 63;
  if (wid >= n) return;
  int start = row_start[wid], end = row_start[wid + 1];
  int deg = end - start;

  float adv[H];
#pragma unroll
  for (int hh = 0; hh < H; hh++) adv[hh] = a_d[wid * H + hh];

  if (deg <= 64) {
    // ---- pass 1 ----
    bool valid = lane < deg;
    int sn = valid ? edge_src[start + lane] : 0;
    float e[H];
    if (valid) {
      if constexpr (H == 4) {
        float4 asv = *(const float4*)(a_s + (size_t)sn * 4);
        float t0 = asv.x + adv[0];
        float t1 = asv.y + adv[1];
        float t2 = asv.z + adv[2];
        float t3 = asv.w + adv[3];
        e[0] = t0 >= 0.f ? t0 : SLOPE * t0;
        e[1] = t1 >= 0.f ? t1 : SLOPE * t1;
        e[2] = t2 >= 0.f ? t2 : SLOPE * t2;
        e[3] = t3 >= 0.f ? t3 : SLOPE * t3;
      } else {
        float tt = a_s[sn] + adv[0];
        e[0] = tt >= 0.f ? tt : SLOPE * tt;
      }
    } else {
#pragma unroll
      for (int hh = 0; hh < H; hh++) e[hh] = -1e30f;
    }
    bool small = (deg <= 32);
    float m[H], w[H], s[H];
#pragma unroll
    for (int hh = 0; hh < H; hh++) m[hh] = e[hh];
#pragma unroll
    for (int off = 1; off <= 16; off <<= 1)
#pragma unroll
      for (int hh = 0; hh < H; hh++)
        m[hh] = fmaxf(m[hh], __shfl_xor(m[hh], off, 64));
    if (!small)
#pragma unroll
      for (int hh = 0; hh < H; hh++)
        m[hh] = fmaxf(m[hh], __shfl_xor(m[hh], 32, 64));
#pragma unroll
    for (int hh = 0; hh < H; hh++) {
      w[hh] = valid ? __expf(e[hh] - m[hh]) : 0.f;
      s[hh] = w[hh];
    }
#pragma unroll
    for (int off = 1; off <= 16; off <<= 1)
#pragma unroll
      for (int hh = 0; hh < H; hh++) s[hh] += __shfl_xor(s[hh], off, 64);
    if (!small)
#pragma unroll
      for (int hh = 0; hh < H; hh++) s[hh] += __shfl_xor(s[hh], 32, 64);
    sn_lds[wslot][lane] = sn;
#pragma unroll
    for (int hh = 0; hh < H; hh++)
      w_lds[wslot][hh * 66 + lane] = valid ? w[hh] * (1.f / s[hh]) : 0.f;
    __builtin_amdgcn_wave_barrier();

    // ---- pass 2: 2 edges in flight, 32 lanes x 4 dims ----
    int g = lane >> 5, l = lane & 31;
    int d0 = l * 4;
    int headBase = (H == 4) ? (l >> 3) * 66 : 0;
    float acc0 = 0.f, acc1 = 0.f, acc2 = 0.f, acc3 = 0.f;
    int degp4 = (deg + 3) & ~3;  // pad slots have w=0, sn=0 (safe row)
    for (int eidx = g; eidx < degp4; eidx += 4) {
#pragma unroll
      for (int jj = 0; jj < 2; jj++) {
        int ei2 = eidx + jj * 2;
        int sn2 = sn_lds[wslot][ei2];
        float wv = w_lds[wslot][headBase + ei2];
        union { float2 f; __half2 h2[2]; } u;
        u.f = *(const float2*)(h + (size_t)sn2 * 128 + d0);
        float2 p0 = __half22float2(u.h2[0]);
        float2 p1 = __half22float2(u.h2[1]);
        acc0 = fmaf(p0.x, wv, acc0);
        acc1 = fmaf(p0.y, wv, acc1);
        acc2 = fmaf(p1.x, wv, acc2);
        acc3 = fmaf(p1.y, wv, acc3);
      }
    }
    acc0 += __shfl_xor(acc0, 32, 64);
    acc1 += __shfl_xor(acc1, 32, 64);
    acc2 += __shfl_xor(acc2, 32, 64);
    acc3 += __shfl_xor(acc3, 32, 64);
    if (lane < 32) {
      float4 bv = *(const float4*)(bias + d0);
      float o0 = acc0 + bv.x, o1 = acc1 + bv.y;
      float o2 = acc2 + bv.z, o3 = acc3 + bv.w;
      if (DO_ELU) {
        o0 = (o0 > 0.f) ? o0 : __expf(o0) - 1.f;
        o1 = (o1 > 0.f) ? o1 : __expf(o1) - 1.f;
        o2 = (o2 > 0.f) ? o2 : __expf(o2) - 1.f;
        o3 = (o3 > 0.f) ? o3 : __expf(o3) - 1.f;
      }
      float4 ov = {o0, o1, o2, o3};
      *(float4*)(out + (size_t)wid * 128 + d0) = ov;
    }
    return;
  }

  // ---- generic fallback (deg > 64) — correctness only, ~never taken ----
  {
    const int G = C / 2;
    int head = lane / G;
    float m[H], s[H];
#pragma unroll
    for (int hh = 0; hh < H; hh++) { m[hh] = -1e30f; s[hh] = 0.f; }
    for (int idx = start + lane; idx < end; idx += 64) {
      int sn = edge_src[idx];
#pragma unroll
      for (int hh = 0; hh < H; hh++) {
        float e = a_s[sn * H + hh] + adv[hh];
        e = (e >= 0.f) ? e : SLOPE * e;
        float mn = fmaxf(m[hh], e);
        s[hh] = s[hh] * __expf(m[hh] - mn) + __expf(e - mn);
        m[hh] = mn;
      }
    }
    for (int off = 1; off < 64; off <<= 1) {
#pragma unroll
      for (int hh = 0; hh < H; hh++) {
        float mo = __shfl_xor(m[hh], off, 64);
        float so = __shfl_xor(s[hh], off, 64);
        float mn = fmaxf(m[hh], mo);
        s[hh] = s[hh] * __expf(m[hh] - mn) + so * __expf(mo - mn);
        m[hh] = mn;
      }
    }
    int d0 = lane * 2;
    float mh = m[head];
    float rsh = 1.f / s[head];
    float adh = adv[head];
    float acc0 = 0.f, acc1 = 0.f;
    for (int idx = start; idx < end; idx++) {
      int sn = edge_src[idx];
      float e = a_s[sn * H + head] + adh;
      e = (e >= 0.f) ? e : SLOPE * e;
      float w = __expf(e - mh) * rsh;
      float2 hv = __half22float2(*(const __half2*)(h + (size_t)sn * 128 + d0));
      acc0 += w * hv.x;
      acc1 += w * hv.y;
    }
    float o0 = acc0 + bias[d0];
    float o1 = acc1 + bias[d0 + 1];
    if (DO_ELU) {
      o0 = (o0 > 0.f) ? o0 : __expf(o0) - 1.f;
      o1 = (o1 > 0.f) ? o1 : __expf(o1) - 1.f;
    }
    out[(size_t)wid * 128 + d0] = o0;
    out[(size_t)wid * 128 + d0 + 1] = o1;
  }
}

extern "C" void kernel_launch(void* const* d_in, const int* in_sizes, int n_in,
                              void* d_out, int out_size, void* d_ws,
                              size_t ws_size, hipStream_t stream) {
  const float* x = (const float*)d_in[0];
  const int* ei = (const int*)d_in[1];
  const float* W1 = (const float*)d_in[2];
  const float* as1 = (const float*)d_in[3];
  const float* ad1 = (const float*)d_in[4];
  const float* b1 = (const float*)d_in[5];
  const float* W2 = (const float*)d_in[6];
  const float* as2 = (const float*)d_in[7];
  const float* ad2 = (const float*)d_in[8];
  const float* b2 = (const float*)d_in[9];
  const float* W3 = (const float*)d_in[10];
  const float* as3 = (const float*)d_in[11];
  const float* ad3 = (const float*)d_in[12];
  const float* b3 = (const float*)d_in[13];
  float* out = (float*)d_out;

  const int n = N_NODES, E = N_EDGES, total = E + n;

  char* ws = (char*)d_ws;
  size_t off = 0;
  auto alloc = [&](size_t bytes) -> char* {
    char* p = ws + off;
    off = (off + bytes + 255) & ~(size_t)255;
    return p;
  };
  __half* hbuf = (__half*)alloc(sizeof(__half) * (size_t)n * 128);  // 25.6 MB
  float* a_s = (float*)alloc(sizeof(float) * n * 4);
  float* a_d = (float*)alloc(sizeof(float) * n * 4);
  unsigned* part = (unsigned*)alloc(sizeof(unsigned) * total);  // 6.8 MB
  int* edge_src = (int*)alloc(sizeof(int) * total);             // 6.8 MB
  int* row_start = (int*)alloc(sizeof(int) * (n + 1));
  int* bucket_count = (int*)alloc(sizeof(int) * (NB + 1));
  int* bucket_base = (int*)alloc(sizeof(int) * (NB + 1));
  int* bucket_cursor = (int*)alloc(sizeof(int) * (NB + 1));
  __half* Wt1 = (__half*)alloc(sizeof(__half) * 16384);
  __half* Wt2 = (__half*)alloc(sizeof(__half) * 16384);
  __half* Wt3 = (__half*)alloc(sizeof(__half) * 16384);

  hipMemsetAsync(bucket_count, 0, sizeof(int) * (NB + 1), stream);

  // weight convert (fp32 -> fp16 transposed) — once per launch
  convert_w<<<192, 256, 0, stream>>>(W1, W2, W3, Wt1, Wt2, Wt3);

  // CSR build via two-level counting sort (graph shared by all 3 layers)
  int nblkA = (total + CHUNK - 1) / CHUNK;  // 208
  partA1<<<nblkA, 256, 0, stream>>>(ei, bucket_count, E, n);
  scan_nb<<<1, 512, 0, stream>>>(bucket_count, bucket_base, bucket_cursor);
  partA2<<<nblkA, 256, 0, stream>>>(ei, bucket_cursor, part, E, n);
  passB<<<NB, 256, 0, stream>>>(part, bucket_base, row_start, edge_src, n);

  int agg_blocks = (n + 3) / 4;        // one wave per node, 4 waves/block
  int gemm_blocks = (n + 63) / 64;     // 64 rows per block

  // layer 1: x -> hbuf(+dots) -> out (ELU)
  gemm_att_mfma<4><<<gemm_blocks, 256, 0, stream>>>(x, Wt1, as1, ad1, hbuf,
                                                    a_s, a_d, n);
  agg_kernel<4, true><<<agg_blocks, 256, 0, stream>>>(
      hbuf, a_s, a_d, row_start, edge_src, b1, out, n);

  // layer 2: out -> hbuf(+dots) -> out (ELU)
  gemm_att_mfma<4><<<gemm_blocks, 256, 0, stream>>>(out, Wt2, as2, ad2, hbuf,
                                                    a_s, a_d, n);
  agg_kernel<4, true><<<agg_blocks, 256, 0, stream>>>(
      hbuf, a_s, a_d, row_start, edge_src, b2, out, n);

  // layer 3: out -> hbuf(+dots) -> out (no ELU), heads=1
  gemm_att_mfma<1><<<gemm_blocks, 256, 0, stream>>>(out, Wt3, as3, ad3, hbuf,
                                                    a_s, a_d, n);
  agg_kernel<1, false><<<agg_blocks, 256, 0, stream>>>(
      hbuf, a_s, a_d, row_start, edge_src, b3, out, n);
}